// Round 11
// baseline (841.284 us; speedup 1.0000x reference)
//
#include <hip/hip_runtime.h>

#define Bsz 8
#define Npts 32
#define Kb 5
#define Mpc 4096
#define NCAD 2048
#define NSTEPS 20
#define NCHUNK 32
#define PPB 128

// consts layout
#define CD_GI 0
#define CD_BMEAN 25
#define CD_WD 40
#define CD_WSUM 72
#define CD_LAMK 74
#define CD_BC 80
// sav layout
#define SV_YC 0
#define SV_B1 96
#define SV_R1 384
#define SV_U1 411
#define SV_C2 477
#define SV_USTR 22

__device__ __forceinline__ float wsum32(float v){
  v += __shfl_xor(v, 1, 64);
  v += __shfl_xor(v, 2, 64);
  v += __shfl_xor(v, 4, 64);
  v += __shfl_xor(v, 8, 64);
  v += __shfl_xor(v,16, 64);
  return v;
}
__device__ __forceinline__ double dsum32(double v){
  v += __shfl_xor(v, 1, 64);
  v += __shfl_xor(v, 2, 64);
  v += __shfl_xor(v, 4, 64);
  v += __shfl_xor(v, 8, 64);
  v += __shfl_xor(v,16, 64);
  return v;
}

__device__ __forceinline__ float det3f(const float M[3][3]){
  return M[0][0]*(M[1][1]*M[2][2]-M[1][2]*M[2][1])
       - M[0][1]*(M[1][0]*M[2][2]-M[1][2]*M[2][0])
       + M[0][2]*(M[1][0]*M[2][1]-M[1][1]*M[2][0]);
}

#define JROTF(p,q,u) { \
  float apq=A[p][q]; \
  if (fabsf(apq)>1e-30f){ \
    float theta=(A[q][q]-A[p][p])/(2.0f*apq); \
    float tt=(theta>=0.0f)?1.0f/(theta+sqrtf(1.0f+theta*theta)):1.0f/(theta-sqrtf(1.0f+theta*theta)); \
    float cc=1.0f/sqrtf(1.0f+tt*tt), ssn=tt*cc; \
    float app=A[p][p], aqq=A[q][q]; \
    A[p][p]=app-tt*apq; A[q][q]=aqq+tt*apq; A[p][q]=0.0f; A[q][p]=0.0f; \
    float aup=A[u][p], auq=A[u][q]; \
    A[u][p]=cc*aup-ssn*auq; A[p][u]=A[u][p]; \
    A[u][q]=ssn*aup+cc*auq; A[q][u]=A[u][q]; \
    for (int i_=0;i_<3;i_++){ float vip=V[i_][p], viq=V[i_][q]; V[i_][p]=cc*vip-ssn*viq; V[i_][q]=ssn*vip+cc*viq; } \
  } }

__device__ void svd3f(const float H[3][3], float U[3][3], float s[3], float V[3][3], float* dsg)
{
  float A[3][3];
  for (int i=0;i<3;i++) for (int j=0;j<3;j++){
    float a=0.0f;
    for (int k=0;k<3;k++) a += H[k][i]*H[k][j];
    A[i][j]=a;
  }
  V[0][0]=1;V[0][1]=0;V[0][2]=0; V[1][0]=0;V[1][1]=1;V[1][2]=0; V[2][0]=0;V[2][1]=0;V[2][2]=1;
  for (int sweep=0; sweep<6; ++sweep){
    float off=fabsf(A[0][1])+fabsf(A[0][2])+fabsf(A[1][2]);
    float dia=fabsf(A[0][0])+fabsf(A[1][1])+fabsf(A[2][2]);
    if (off <= 3e-7f*dia + 1e-30f) break;
    JROTF(0,1,2)
    JROTF(0,2,1)
    JROTF(1,2,0)
  }
  float e0=A[0][0], e1=A[1][1], e2=A[2][2];
  if (e0<e1){ float t=e0;e0=e1;e1=t; for(int i=0;i<3;i++){float tv=V[i][0];V[i][0]=V[i][1];V[i][1]=tv;} }
  if (e0<e2){ float t=e0;e0=e2;e2=t; for(int i=0;i<3;i++){float tv=V[i][0];V[i][0]=V[i][2];V[i][2]=tv;} }
  if (e1<e2){ float t=e1;e1=e2;e2=t; for(int i=0;i<3;i++){float tv=V[i][1];V[i][1]=V[i][2];V[i][2]=tv;} }
  for (int c=0;c<3;c++){
    float u0=H[0][0]*V[0][c]+H[0][1]*V[1][c]+H[0][2]*V[2][c];
    float u1=H[1][0]*V[0][c]+H[1][1]*V[1][c]+H[1][2]*V[2][c];
    float u2=H[2][0]*V[0][c]+H[2][1]*V[1][c]+H[2][2]*V[2][c];
    float nr=sqrtf(u0*u0+u1*u1+u2*u2);
    s[c]=nr;
    float inv=(nr>1e-30f)?1.0f/nr:0.0f;
    U[0][c]=u0*inv; U[1][c]=u1*inv; U[2][c]=u2*inv;
  }
  if (s[2] <= 1e-6f*s[0]){
    U[0][2]=U[1][0]*U[2][1]-U[2][0]*U[1][1];
    U[1][2]=U[2][0]*U[0][1]-U[0][0]*U[2][1];
    U[2][2]=U[0][0]*U[1][1]-U[1][0]*U[0][1];
  }
  float dd=det3f(U)*det3f(V);
  *dsg = (dd>=0.0f)?1.0f:-1.0f;
}

__device__ void proc_bwd(const float dRm[3][3], const float* sv, float dH[3][3])
{
  float U[3][3],V[3][3],s[3],dsg;
  for (int i=0;i<3;i++) for (int j=0;j<3;j++){ U[i][j]=sv[i*3+j]; V[i][j]=sv[12+i*3+j]; }
  s[0]=sv[9]; s[1]=sv[10]; s[2]=sv[11];
  dsg=sv[21];
  float A0[3][3];
  for (int a=0;a<3;a++) for (int c=0;c<3;c++){
    float x=0.0f;
    for (int i=0;i<3;i++) for (int j=0;j<3;j++) x += U[i][a]*dRm[i][j]*V[j][c];
    A0[a][c]=x;
  }
  float D[3]={1.0f,1.0f,dsg};
  float Q[3][3]={{0,0,0},{0,0,0},{0,0,0}};
  for (int i=0;i<3;i++) for (int j=0;j<3;j++){
    if (i==j) continue;
    float Muu=A0[i][j]*D[j]-D[i]*A0[j][i];
    float Mvv=A0[j][i]*D[j]-D[i]*A0[i][j];
    float den=s[j]*s[j]-s[i]*s[i];
    if (fabsf(den)<1e-18f) den=(den>=0.0f?1e-18f:-1e-18f);
    Q[i][j]=(Muu*s[j]+s[i]*Mvv)/den;
  }
  for (int i=0;i<3;i++) for (int j=0;j<3;j++){
    float x=0.0f;
    for (int a=0;a<3;a++) for (int c=0;c<3;c++) x += U[i][a]*Q[a][c]*V[j][c];
    dH[i][j]=x;
  }
}

__device__ void pace_fwd_wave(const float y[3], const float* consts, float* sav,
                              int lane, int save,
                              float R3[3][3], float tvec[3], float cout[Kb])
{
  int n = lane & 31;
  const float* Gi=consts+CD_GI;
  const float* Bmean=consts+CD_BMEAN;
  float wsum=consts[CD_WSUM], lamK=consts[CD_LAMK];
  float wd_n=consts[CD_WD+n];
  float Bc_n[15];
  for (int e=0;e<15;e++) Bc_n[e]=consts[CD_BC+e*Npts+n];

  float ymean[3], yc[3];
  for (int i=0;i<3;i++) ymean[i]=wsum32(y[i]*wd_n)/wsum;
  for (int i=0;i<3;i++) yc[i]=y[i]-ymean[i];
  if (save && lane<32) for (int i=0;i<3;i++) sav[SV_YC+i*Npts+n]=yc[i];

  float c[Kb];
  for (int k=0;k<Kb;k++) c[k]=1.0f/(float)Kb;

  for (int r=0;r<3;r++){
    float bb[3];
    for (int i=0;i<3;i++){
      float a=0.0f;
      for (int k=0;k<Kb;k++) a+=c[k]*Bc_n[k*3+i];
      bb[i]=a;
    }
    float H[3][3];
    for (int i=0;i<3;i++){
      float wy=yc[i]*wd_n;
      for (int j=0;j<3;j++) H[i][j]=wsum32(wy*bb[j]);
    }
    float U[3][3],V[3][3],s[3],dsg;
    svd3f(H,U,s,V,&dsg);
    float R[3][3];
    for (int i=0;i<3;i++) for (int j=0;j<3;j++)
      R[i][j]=U[i][0]*V[j][0]+U[i][1]*V[j][1]+dsg*U[i][2]*V[j][2];

    if (save){
      if (lane<32) for (int i=0;i<3;i++) sav[SV_B1+r*96+i*Npts+n]=bb[i];
      if (lane==0){
        float* pr=sav+SV_R1+r*9;
        for (int i=0;i<3;i++) for (int j=0;j<3;j++) pr[i*3+j]=R[i][j];
        float* pu=sav+SV_U1+r*SV_USTR;
        for (int i=0;i<3;i++) for (int j=0;j<3;j++){ pu[i*3+j]=U[i][j]; pu[12+i*3+j]=V[i][j]; }
        pu[9]=s[0]; pu[10]=s[1]; pu[11]=s[2]; pu[21]=dsg;
      }
    }

    if (r<2){
      float yr[3];
      for (int i=0;i<3;i++) yr[i]=R[0][i]*yc[0]+R[1][i]*yc[1]+R[2][i]*yc[2];
      float h[Kb];
      for (int k=0;k<Kb;k++){
        float p=(Bc_n[k*3+0]*yr[0]+Bc_n[k*3+1]*yr[1]+Bc_n[k*3+2]*yr[2])*wd_n;
        h[k]=wsum32(p)+lamK;
      }
      for (int k=0;k<Kb;k++){
        float a=0.0f;
        for (int l=0;l<Kb;l++) a+=Gi[k*Kb+l]*h[l];
        c[k]=a;
      }
    } else {
      for (int i=0;i<3;i++) for (int j=0;j<3;j++) R3[i][j]=R[i][j];
    }
  }
  float bmean[3];
  for (int i=0;i<3;i++){
    float a=0.0f;
    for (int k=0;k<Kb;k++) a+=c[k]*Bmean[k*3+i];
    bmean[i]=a;
  }
  for (int i=0;i<3;i++)
    tvec[i]=ymean[i]-(R3[i][0]*bmean[0]+R3[i][1]*bmean[1]+R3[i][2]*bmean[2]);
  for (int k=0;k<Kb;k++) cout[k]=c[k];
  if (save && lane==0) for (int k=0;k<Kb;k++) sav[SV_C2+k]=c[k];
}

__device__ void pace_bwd_wave(const float red[17], const float* consts, const float* sav,
                              int lane, float dy[3])
{
  int n = lane & 31;
  const float* Gi=consts+CD_GI;
  const float* Bmean=consts+CD_BMEAN;
  float wsum=consts[CD_WSUM];
  float wd_n=consts[CD_WD+n];
  float Bc_n[15];
  for (int e=0;e<15;e++) Bc_n[e]=consts[CD_BC+e*Npts+n];
  float yc[3], b0v[3], b1v[3], b2v[3];
  for (int i=0;i<3;i++){
    yc[i] =sav[SV_YC+i*Npts+n];
    b0v[i]=sav[SV_B1+0*96+i*Npts+n];
    b1v[i]=sav[SV_B1+1*96+i*Npts+n];
    b2v[i]=sav[SV_B1+2*96+i*Npts+n];
  }
  float c2[Kb];
  for (int k=0;k<Kb;k++) c2[k]=sav[SV_C2+k];
  float R3[3][3];
  for (int i=0;i<3;i++) for (int j=0;j<3;j++) R3[i][j]=sav[SV_R1+18+i*3+j];

  float dt[3]={red[0],red[1],red[2]};
  float dRm[3][3];
  for (int i=0;i<3;i++) for (int j=0;j<3;j++) dRm[i][j]=red[3+i*3+j];
  float dc[Kb];
  for (int k=0;k<Kb;k++) dc[k]=red[12+k];

  float bmean[3];
  for (int i=0;i<3;i++){ float a=0.0f; for (int k=0;k<Kb;k++) a+=c2[k]*Bmean[k*3+i]; bmean[i]=a; }
  for (int i=0;i<3;i++) for (int j=0;j<3;j++) dRm[i][j]-=dt[i]*bmean[j];
  float dbm[3];
  for (int i=0;i<3;i++) dbm[i]=-(R3[0][i]*dt[0]+R3[1][i]*dt[1]+R3[2][i]*dt[2]);
  for (int k=0;k<Kb;k++) dc[k]+=dbm[0]*Bmean[k*3+0]+dbm[1]*Bmean[k*3+1]+dbm[2]*Bmean[k*3+2];

  float dH[3][3];
  proc_bwd(dRm, sav+SV_U1+2*SV_USTR, dH);
  float dyc[3];
  for (int i=0;i<3;i++)
    dyc[i]=wd_n*(dH[i][0]*b2v[0]+dH[i][1]*b2v[1]+dH[i][2]*b2v[2]);
  {
    float dcp[Kb]={0,0,0,0,0};
    for (int j=0;j<3;j++){
      float db=wd_n*(dH[0][j]*yc[0]+dH[1][j]*yc[1]+dH[2][j]*yc[2]);
      for (int k=0;k<Kb;k++) dcp[k]+=db*Bc_n[k*3+j];
    }
    for (int k=0;k<Kb;k++) dc[k]+=wsum32(dcp[k]);
  }
  #pragma unroll
  for (int it=1; it>=0; --it){
    float dh[Kb];
    for (int k=0;k<Kb;k++){ float a=0.0f; for (int l=0;l<Kb;l++) a+=Gi[k*Kb+l]*dc[l]; dh[k]=a; }
    float dyr[3];
    for (int i=0;i<3;i++){
      float a=0.0f;
      for (int k=0;k<Kb;k++) a+=dh[k]*Bc_n[k*3+i];
      dyr[i]=wd_n*a;
    }
    float dR2[3][3];
    for (int j=0;j<3;j++) for (int i=0;i<3;i++) dR2[j][i]=wsum32(yc[j]*dyr[i]);
    float Rr[9];
    for (int e=0;e<9;e++) Rr[e]=sav[SV_R1+it*9+e];
    for (int j=0;j<3;j++) dyc[j]+=Rr[j*3+0]*dyr[0]+Rr[j*3+1]*dyr[1]+Rr[j*3+2]*dyr[2];
    proc_bwd(dR2, sav+SV_U1+it*SV_USTR, dH);
    float bs0,bs1,bs2;
    if (it==1){ bs0=b1v[0]; bs1=b1v[1]; bs2=b1v[2]; }
    else      { bs0=b0v[0]; bs1=b0v[1]; bs2=b0v[2]; }
    for (int i=0;i<3;i++) dyc[i]+=wd_n*(dH[i][0]*bs0+dH[i][1]*bs1+dH[i][2]*bs2);
    if (it>0){
      float dcp[Kb]={0,0,0,0,0};
      for (int j=0;j<3;j++){
        float db=wd_n*(dH[0][j]*yc[0]+dH[1][j]*yc[1]+dH[2][j]*yc[2]);
        for (int k=0;k<Kb;k++) dcp[k]+=db*Bc_n[k*3+j];
      }
      for (int k=0;k<Kb;k++) dc[k]=wsum32(dcp[k]);
    }
  }
  for (int i=0;i<3;i++){
    float S=wsum32(dyc[i]);
    dy[i]=dyc[i]+wd_n/wsum*(dt[i]-S);
  }
}

// fp64 consts, static pivot-free GJ (G is SPD + lam ridge) -> all registers
__device__ void compute_consts_static(const float* mkp, const float* w, const float* lamp,
                                      int lane, float* cl)
{
  int n=lane&31;
  double wv=(double)w[n];
  double wsum=dsum32(wv);
  double mk[15], Bm[15], Bc_n[15];
  #pragma unroll
  for (int e=0;e<15;e++) mk[e]=(double)mkp[e*Npts+n];
  #pragma unroll
  for (int e=0;e<15;e++) Bm[e]=dsum32(mk[e]*wv)/wsum;
  #pragma unroll
  for (int e=0;e<15;e++) Bc_n[e]=mk[e]-Bm[e];
  double lam=(double)lamp[0];
  double G[Kb][Kb], GI[Kb][Kb];
  #pragma unroll
  for (int k=0;k<Kb;k++)
  #pragma unroll
  for (int l=0;l<Kb;l++){
    double p=(Bc_n[k*3+0]*Bc_n[l*3+0]+Bc_n[k*3+1]*Bc_n[l*3+1]+Bc_n[k*3+2]*Bc_n[l*3+2])*wv;
    G[k][l]=dsum32(p)+((k==l)?lam:0.0);
    GI[k][l]=(k==l)?1.0:0.0;
  }
  #pragma unroll
  for (int col=0;col<Kb;col++){
    double ip=1.0/G[col][col];
    #pragma unroll
    for (int j=0;j<Kb;j++){ G[col][j]*=ip; GI[col][j]*=ip; }
    #pragma unroll
    for (int r=0;r<Kb;r++){
      if (r==col) continue;
      double f=G[r][col];
      #pragma unroll
      for (int j=0;j<Kb;j++){ G[r][j]-=f*G[col][j]; GI[r][j]-=f*GI[col][j]; }
    }
  }
  if (lane<32){
    cl[CD_WD+n]=(float)wv;
    #pragma unroll
    for (int e=0;e<15;e++) cl[CD_BC+e*Npts+n]=(float)Bc_n[e];
  }
  if (lane==0){
    cl[CD_WSUM]=(float)wsum;
    cl[CD_LAMK]=(float)(lam/(double)Kb);
    #pragma unroll
    for (int e=0;e<15;e++) cl[CD_BMEAN+e]=(float)Bm[e];
    #pragma unroll
    for (int k=0;k<Kb;k++)
    #pragma unroll
    for (int l=0;l<Kb;l++) cl[CD_GI+k*Kb+l]=(float)GI[k][l];
  }
}

// ---------------- kernels ----------------
__global__ void k_init(const float* __restrict__ kp, const float* __restrict__ corr0,
                       const float* __restrict__ mkp, const float* __restrict__ w,
                       const float* __restrict__ lamp,
                       float* __restrict__ consts, float* __restrict__ posebuf,
                       float* __restrict__ corrbuf, float* __restrict__ savbuf)
{
  int b=blockIdx.x, lane=threadIdx.x, n=lane&31;
  __shared__ float cl[560];
  compute_consts_static(mkp, w, lamp, lane, cl);
  for (int e=lane;e<96;e+=64) corrbuf[b*96+e]=corr0[b*96+e];
  float y[3];
  for (int i=0;i<3;i++) y[i]=kp[b*96+i*Npts+n]+corr0[b*96+i*Npts+n];
  float R3[3][3],tv[3],cc[Kb];
  pace_fwd_wave(y, cl, savbuf+(size_t)b*512, lane, 1, R3, tv, cc);
  if (lane==0){
    float* P=posebuf+b*20;
    for (int i=0;i<3;i++){ P[9+i]=tv[i]; for (int j=0;j<3;j++) P[i*3+j]=R3[i][j]; }
    for (int k=0;k<Kb;k++) P[12+k]=cc[k];
  }
  if (b==0) for (int e=lane;e<560;e+=64) consts[e]=cl[e];
}

// k_step: 256 blocks x 512 thr. [s>0: redundant PACE update] + chamfer (4 pts/thread,
// prefetch-pipelined LDS reads) + 17-sum
__global__ __launch_bounds__(512,1) void k_step(const float* __restrict__ pc,
    const float* __restrict__ kp, const float* __restrict__ cad,
    const float* __restrict__ consts, const float* __restrict__ posebuf,
    float* __restrict__ corrbuf, float* __restrict__ savbuf,
    float* __restrict__ accbuf, int step)
{
  int blk=blockIdx.x;
  int b=blk>>5, chunk=blk&31;
  int tid=threadIdx.x;
  __shared__ float4 smod[NCAD];
  __shared__ float s_cl[560];
  __shared__ float s_sav[512];
  __shared__ float s_pose[20];
  __shared__ float s_part[8][17];

  int wsel=step&1, rsel=1-wsel;
  float* acc_w = accbuf + (size_t)wsel*(Bsz*NCHUNK*20);
  const float* acc_r = accbuf + (size_t)rsel*(Bsz*NCHUNK*20);
  const float* corr_r = corrbuf + rsel*(Bsz*96) + b*96;
  float* corr_w = corrbuf + wsel*(Bsz*96) + b*96;
  const float* sav_r = savbuf + (size_t)rsel*(Bsz*512) + b*512;
  float* sav_w = savbuf + (size_t)wsel*(Bsz*512) + b*512;

  if (tid<64){
    int lane=tid, n=lane&31;
    for (int e=lane;e<560;e+=64) s_cl[e]=consts[e];
    if (step==0){
      if (lane<20) s_pose[lane]=posebuf[b*20+lane];
    } else {
      for (int e=lane;e<512;e+=64) s_sav[e]=sav_r[e];
      float red[17];
      if (lane<17){
        float a=0.f;
        for (int ch=0;ch<NCHUNK;ch++) a+=acc_r[(b*NCHUNK+ch)*20+lane];
        s_part[0][lane]=a*(2.0f/(float)Mpc);
      }
      for (int v=0;v<17;v++) red[v]=s_part[0][v];
      float dy[3];
      pace_bwd_wave(red, s_cl, s_sav, lane, dy);
      float newc[3];
      for (int i=0;i<3;i++) newc[i]=corr_r[i*Npts+n]-0.5f*dy[i];
      float y[3];
      for (int i=0;i<3;i++) y[i]=kp[b*96+i*Npts+n]+newc[i];
      float R3[3][3],tv[3],cc[Kb];
      pace_fwd_wave(y, s_cl, s_sav, lane, 1, R3, tv, cc);
      if (lane==0){
        for (int i=0;i<3;i++){ s_pose[9+i]=tv[i]; for (int j=0;j<3;j++) s_pose[i*3+j]=R3[i][j]; }
        for (int k=0;k<Kb;k++) s_pose[12+k]=cc[k];
      }
      if (chunk==0){
        if (lane<32) for (int i=0;i<3;i++) corr_w[i*Npts+n]=newc[i];
        for (int e=lane;e<512;e+=64) sav_w[e]=s_sav[e];
      }
    }
  }
  __syncthreads();

  float R[9],T[3],C[Kb];
  for (int e=0;e<9;e++) R[e]=s_pose[e];
  for (int i=0;i<3;i++) T[i]=s_pose[9+i];
  for (int k=0;k<Kb;k++) C[k]=s_pose[12+k];
  // build rotated model + |.|^2 into LDS (4 j per thread)
  for (int j=tid;j<NCAD;j+=512){
    float cv[15];
    for (int e=0;e<15;e++) cv[e]=cad[e*NCAD+j];
    float m0=0.f,m1=0.f,m2=0.f;
    for (int k=0;k<Kb;k++){ m0+=C[k]*cv[k*3+0]; m1+=C[k]*cv[k*3+1]; m2+=C[k]*cv[k*3+2]; }
    float ax=R[0]*m0+R[1]*m1+R[2]*m2+T[0];
    float ay=R[3]*m0+R[4]*m1+R[5]*m2+T[1];
    float az=R[6]*m0+R[7]*m1+R[8]*m2+T[2];
    smod[j]=make_float4(ax,ay,az, ax*ax+ay*ay+az*az);
  }
  __syncthreads();
  // argmin: 4 points/thread, 16 threads/point-group (j stride 16), explicit prefetch pipeline
  int pr=tid>>4, q=tid&15;
  int pbase=chunk*PPB+pr*4;
  const float* pcb=pc+(size_t)b*3*Mpc;
  float px0=pcb[pbase+0],       px1=pcb[pbase+1],       px2=pcb[pbase+2],       px3=pcb[pbase+3];
  float py0=pcb[Mpc+pbase+0],   py1=pcb[Mpc+pbase+1],   py2=pcb[Mpc+pbase+2],   py3=pcb[Mpc+pbase+3];
  float pz0=pcb[2*Mpc+pbase+0], pz1=pcb[2*Mpc+pbase+1], pz2=pcb[2*Mpc+pbase+2], pz3=pcb[2*Mpc+pbase+3];
  float nx0=-2.f*px0, nx1=-2.f*px1, nx2=-2.f*px2, nx3=-2.f*px3;
  float ny0=-2.f*py0, ny1=-2.f*py1, ny2=-2.f*py2, ny3=-2.f*py3;
  float nz0=-2.f*pz0, nz1=-2.f*pz1, nz2=-2.f*pz2, nz3=-2.f*pz3;
  float d0=3.4e38f, d1=3.4e38f, d2=3.4e38f, d3=3.4e38f;
  int j0=0, j1=0, j2=0, j3=0;
  float4 mcur=smod[q];
  int jc=q;
  #pragma unroll 8
  for (int it=0; it<NCAD/16-1; ++it){
    float4 mnext=smod[jc+16];           // prefetch next tile under current compute
    float c;
    c=fmaf(nx0,mcur.x,fmaf(ny0,mcur.y,fmaf(nz0,mcur.z,mcur.w))); if(c<d0){d0=c;j0=jc;}
    c=fmaf(nx1,mcur.x,fmaf(ny1,mcur.y,fmaf(nz1,mcur.z,mcur.w))); if(c<d1){d1=c;j1=jc;}
    c=fmaf(nx2,mcur.x,fmaf(ny2,mcur.y,fmaf(nz2,mcur.z,mcur.w))); if(c<d2){d2=c;j2=jc;}
    c=fmaf(nx3,mcur.x,fmaf(ny3,mcur.y,fmaf(nz3,mcur.z,mcur.w))); if(c<d3){d3=c;j3=jc;}
    mcur=mnext; jc+=16;
  }
  {
    float c;
    c=fmaf(nx0,mcur.x,fmaf(ny0,mcur.y,fmaf(nz0,mcur.z,mcur.w))); if(c<d0){d0=c;j0=jc;}
    c=fmaf(nx1,mcur.x,fmaf(ny1,mcur.y,fmaf(nz1,mcur.z,mcur.w))); if(c<d1){d1=c;j1=jc;}
    c=fmaf(nx2,mcur.x,fmaf(ny2,mcur.y,fmaf(nz2,mcur.z,mcur.w))); if(c<d2){d2=c;j2=jc;}
    c=fmaf(nx3,mcur.x,fmaf(ny3,mcur.y,fmaf(nz3,mcur.z,mcur.w))); if(c<d3){d3=c;j3=jc;}
  }
  // combine within aligned 16-lane groups (smaller j on ties)
  #pragma unroll
  for (int mm=1;mm<=8;mm<<=1){
    float od; int oj;
    od=__shfl_xor(d0,mm,64); oj=__shfl_xor(j0,mm,64); if(od<d0||(od==d0&&oj<j0)){d0=od;j0=oj;}
    od=__shfl_xor(d1,mm,64); oj=__shfl_xor(j1,mm,64); if(od<d1||(od==d1&&oj<j1)){d1=od;j1=oj;}
    od=__shfl_xor(d2,mm,64); oj=__shfl_xor(j2,mm,64); if(od<d2||(od==d2&&oj<j2)){d2=od;j2=oj;}
    od=__shfl_xor(d3,mm,64); oj=__shfl_xor(j3,mm,64); if(od<d3||(od==d3&&oj<j3)){d3=od;j3=oj;}
  }
  // per-point gradient -> 17 partial sums (lanes q<4 own point pbase+q)
  float vals[17];
  for (int v=0;v<17;v++) vals[v]=0.f;
  if (q<4){
    float selx=(q==0)?px0:(q==1)?px1:(q==2)?px2:px3;
    float sely=(q==0)?py0:(q==1)?py1:(q==2)?py2:py3;
    float selz=(q==0)?pz0:(q==1)?pz1:(q==2)?pz2:pz3;
    int   selj=(q==0)?j0 :(q==1)?j1 :(q==2)?j2 :j3;
    float4 m=smod[selj];
    float md0=m.x-selx, md1=m.y-sely, md2=m.z-selz;
    float cv[15];
    for (int e=0;e<15;e++) cv[e]=cad[e*NCAD+selj];
    float m00=0.f,m01=0.f,m02=0.f;
    for (int k=0;k<Kb;k++){ m00+=C[k]*cv[k*3+0]; m01+=C[k]*cv[k*3+1]; m02+=C[k]*cv[k*3+2]; }
    vals[0]=md0; vals[1]=md1; vals[2]=md2;
    vals[3]=md0*m00; vals[4]=md0*m01; vals[5]=md0*m02;
    vals[6]=md1*m00; vals[7]=md1*m01; vals[8]=md1*m02;
    vals[9]=md2*m00; vals[10]=md2*m01; vals[11]=md2*m02;
    float t0=R[0]*md0+R[3]*md1+R[6]*md2;
    float t1=R[1]*md0+R[4]*md1+R[7]*md2;
    float t2=R[2]*md0+R[5]*md1+R[8]*md2;
    for (int k=0;k<Kb;k++) vals[12+k]=t0*cv[k*3+0]+t1*cv[k*3+1]+t2*cv[k*3+2];
  }
  for (int mm=1;mm<64;mm<<=1)
    for (int v=0;v<17;v++) vals[v]+=__shfl_xor(vals[v],mm,64);
  int wv=tid>>6;
  if ((tid&63)==0) for (int v=0;v<17;v++) s_part[wv][v]=vals[v];
  __syncthreads();
  if (tid<17){
    float a=0.f;
    for (int w=0;w<8;w++) a+=s_part[w][tid];
    acc_w[(b*NCHUNK+chunk)*20+tid]=a;
  }
}

// k_fin: update #20 + final PACE fwd -> outputs. 8 blocks x 64 thr.
__global__ void k_fin(const float* __restrict__ kp, const float* __restrict__ consts,
                      const float* __restrict__ corrbuf, const float* __restrict__ savbuf,
                      const float* __restrict__ accbuf, float* __restrict__ out)
{
  int b=blockIdx.x, lane=threadIdx.x, n=lane&31;
  // step==NSTEPS(20): rsel = 1-(20&1) = 1
  const float* acc_r = accbuf + (size_t)1*(Bsz*NCHUNK*20);
  const float* corr_r = corrbuf + 1*(Bsz*96) + b*96;
  const float* sav_r = savbuf + (size_t)1*(Bsz*512) + b*512;
  __shared__ float s_cl[560];
  __shared__ float s_sav[512];
  __shared__ float s_red[17];
  for (int e=lane;e<560;e+=64) s_cl[e]=consts[e];
  for (int e=lane;e<512;e+=64) s_sav[e]=sav_r[e];
  if (lane<17){
    float a=0.f;
    for (int ch=0;ch<NCHUNK;ch++) a+=acc_r[(b*NCHUNK+ch)*20+lane];
    s_red[lane]=a*(2.0f/(float)Mpc);
  }
  __syncthreads();
  float red[17];
  for (int v=0;v<17;v++) red[v]=s_red[v];
  float dy[3];
  pace_bwd_wave(red, s_cl, s_sav, lane, dy);
  float newc[3];
  for (int i=0;i<3;i++) newc[i]=corr_r[i*Npts+n]-0.5f*dy[i];
  float y[3];
  for (int i=0;i<3;i++) y[i]=kp[b*96+i*Npts+n]+newc[i];
  float R3[3][3],tv[3],cc[Kb];
  pace_fwd_wave(y, s_cl, s_sav, lane, 0, R3, tv, cc);
  if (lane==0){
    for (int i=0;i<3;i++) for (int j=0;j<3;j++) out[b*9+i*3+j]=R3[i][j];
    for (int i=0;i<3;i++) out[72+b*3+i]=tv[i];
    for (int k=0;k<Kb;k++) out[96+b*Kb+k]=cc[k];
  }
  if (lane<32){
    for (int i=0;i<3;i++){
      out[136+b*96+i*Npts+n]=newc[i];
      out[904+b*96+i*Npts+n]=kp[b*96+i*Npts+n]+newc[i];
    }
  }
}

extern "C" void kernel_launch(void* const* d_in, const int* in_sizes, int n_in,
                              void* d_out, int out_size, void* d_ws, size_t ws_size,
                              hipStream_t stream) {
  const float* pc   =(const float*)d_in[0];
  const float* kp   =(const float*)d_in[1];
  const float* corr0=(const float*)d_in[2];
  const float* mkp  =(const float*)d_in[3];
  const float* cad  =(const float*)d_in[4];
  const float* w    =(const float*)d_in[5];
  const float* lam  =(const float*)d_in[6];
  float* out=(float*)d_out;
  char* ws=(char*)d_ws;
  float* consts =(float*)(ws+0);        // 560
  float* posebuf=(float*)(ws+4096);     // 160
  float* corrbuf=(float*)(ws+8192);     // 2*768
  float* savbuf =(float*)(ws+16384);    // 2*4096
  float* accbuf =(float*)(ws+49152);    // 2*5120

  hipLaunchKernelGGL(k_init, dim3(Bsz), dim3(64), 0, stream,
                     kp, corr0, mkp, w, lam, consts, posebuf, corrbuf, savbuf);
  for (int s=0; s<NSTEPS; ++s){
    hipLaunchKernelGGL(k_step, dim3(Bsz*NCHUNK), dim3(512), 0, stream,
                       pc, kp, cad, consts, posebuf, corrbuf, savbuf, accbuf, s);
  }
  hipLaunchKernelGGL(k_fin, dim3(Bsz), dim3(64), 0, stream,
                     kp, consts, corrbuf, savbuf, accbuf, out);
}

// Round 13
// 783.597 us; speedup vs baseline: 1.0736x; 1.0736x over previous
//
#include <hip/hip_runtime.h>

#define Bsz 8
#define Npts 32
#define Kb 5
#define Mpc 4096
#define NCAD 2048
#define NSTEPS 20
#define NCHUNK 32
#define PPB 128

// consts layout
#define CD_GI 0
#define CD_BMEAN 25
#define CD_WD 40
#define CD_WSUM 72
#define CD_LAMK 74
#define CD_BC 80
// sav layout
#define SV_YC 0
#define SV_B1 96
#define SV_R1 384
#define SV_U1 411
#define SV_C2 477
#define SV_USTR 22

// ---------- DPP-based wave reductions (no LDS-crossbar shuffles) ----------
// dpp_ctrl: 0xB1 quad_perm[1,0,3,2]=xor1, 0x4E quad_perm[2,3,0,1]=xor2,
// 0x141 row_half_mirror (==xor4 once quads uniform), 0x140 row_mirror (==xor8 once
// 8-groups uniform), 0x142 row_bcast15 (rows 1,3), 0x143 row_bcast31 (rows 2,3).
template<int CTRL,int RM,bool BC>
__device__ __forceinline__ float fdpp_add(float v){
  int t=__builtin_amdgcn_update_dpp(0, __float_as_int(v), CTRL, RM, 0xf, BC);
  return v+__int_as_float(t);
}
// exact sum over all 64 lanes, uniform result
__device__ __forceinline__ float wsum64(float v){
  v=fdpp_add<0xB1,0xf,true>(v);
  v=fdpp_add<0x4E,0xf,true>(v);
  v=fdpp_add<0x141,0xf,true>(v);
  v=fdpp_add<0x140,0xf,true>(v);
  v=fdpp_add<0x142,0xa,false>(v);
  v=fdpp_add<0x143,0xc,false>(v);
  return __int_as_float(__builtin_amdgcn_readlane(__float_as_int(v),63));
}
// sum over lanes 0..31 when lanes 32..63 mirror them exactly
__device__ __forceinline__ float wsum32(float v){ return 0.5f*wsum64(v); }

template<int CTRL,int RM,bool BC>
__device__ __forceinline__ double ddpp_add(double v){
  int lo=__builtin_amdgcn_update_dpp(0, __double2loint(v), CTRL, RM, 0xf, BC);
  int hi=__builtin_amdgcn_update_dpp(0, __double2hiint(v), CTRL, RM, 0xf, BC);
  return v+__hiloint2double(hi,lo);
}
__device__ __forceinline__ double dsum32(double v){
  v=ddpp_add<0xB1,0xf,true>(v);
  v=ddpp_add<0x4E,0xf,true>(v);
  v=ddpp_add<0x141,0xf,true>(v);
  v=ddpp_add<0x140,0xf,true>(v);
  v=ddpp_add<0x142,0xa,false>(v);
  v=ddpp_add<0x143,0xc,false>(v);
  int lo=__builtin_amdgcn_readlane(__double2loint(v),63);
  int hi=__builtin_amdgcn_readlane(__double2hiint(v),63);
  return 0.5*__hiloint2double(hi,lo);
}

__device__ __forceinline__ float det3f(const float M[3][3]){
  return M[0][0]*(M[1][1]*M[2][2]-M[1][2]*M[2][1])
       - M[0][1]*(M[1][0]*M[2][2]-M[1][2]*M[2][0])
       + M[0][2]*(M[1][0]*M[2][1]-M[1][1]*M[2][0]);
}

#define JROTF(p,q,u) { \
  float apq=A[p][q]; \
  if (fabsf(apq)>1e-30f){ \
    float theta=(A[q][q]-A[p][p])/(2.0f*apq); \
    float tt=(theta>=0.0f)?1.0f/(theta+sqrtf(1.0f+theta*theta)):1.0f/(theta-sqrtf(1.0f+theta*theta)); \
    float cc=1.0f/sqrtf(1.0f+tt*tt), ssn=tt*cc; \
    float app=A[p][p], aqq=A[q][q]; \
    A[p][p]=app-tt*apq; A[q][q]=aqq+tt*apq; A[p][q]=0.0f; A[q][p]=0.0f; \
    float aup=A[u][p], auq=A[u][q]; \
    A[u][p]=cc*aup-ssn*auq; A[p][u]=A[u][p]; \
    A[u][q]=ssn*aup+cc*auq; A[q][u]=A[u][q]; \
    for (int i_=0;i_<3;i_++){ float vip=V[i_][p], viq=V[i_][q]; V[i_][p]=cc*vip-ssn*viq; V[i_][q]=ssn*vip+cc*viq; } \
  } }

__device__ void svd3f(const float H[3][3], float U[3][3], float s[3], float V[3][3], float* dsg)
{
  float A[3][3];
  for (int i=0;i<3;i++) for (int j=0;j<3;j++){
    float a=0.0f;
    for (int k=0;k<3;k++) a += H[k][i]*H[k][j];
    A[i][j]=a;
  }
  V[0][0]=1;V[0][1]=0;V[0][2]=0; V[1][0]=0;V[1][1]=1;V[1][2]=0; V[2][0]=0;V[2][1]=0;V[2][2]=1;
  for (int sweep=0; sweep<6; ++sweep){
    float off=fabsf(A[0][1])+fabsf(A[0][2])+fabsf(A[1][2]);
    float dia=fabsf(A[0][0])+fabsf(A[1][1])+fabsf(A[2][2]);
    if (off <= 3e-7f*dia + 1e-30f) break;
    JROTF(0,1,2)
    JROTF(0,2,1)
    JROTF(1,2,0)
  }
  float e0=A[0][0], e1=A[1][1], e2=A[2][2];
  if (e0<e1){ float t=e0;e0=e1;e1=t; for(int i=0;i<3;i++){float tv=V[i][0];V[i][0]=V[i][1];V[i][1]=tv;} }
  if (e0<e2){ float t=e0;e0=e2;e2=t; for(int i=0;i<3;i++){float tv=V[i][0];V[i][0]=V[i][2];V[i][2]=tv;} }
  if (e1<e2){ float t=e1;e1=e2;e2=t; for(int i=0;i<3;i++){float tv=V[i][1];V[i][1]=V[i][2];V[i][2]=tv;} }
  for (int c=0;c<3;c++){
    float u0=H[0][0]*V[0][c]+H[0][1]*V[1][c]+H[0][2]*V[2][c];
    float u1=H[1][0]*V[0][c]+H[1][1]*V[1][c]+H[1][2]*V[2][c];
    float u2=H[2][0]*V[0][c]+H[2][1]*V[1][c]+H[2][2]*V[2][c];
    float nr=sqrtf(u0*u0+u1*u1+u2*u2);
    s[c]=nr;
    float inv=(nr>1e-30f)?1.0f/nr:0.0f;
    U[0][c]=u0*inv; U[1][c]=u1*inv; U[2][c]=u2*inv;
  }
  if (s[2] <= 1e-6f*s[0]){
    U[0][2]=U[1][0]*U[2][1]-U[2][0]*U[1][1];
    U[1][2]=U[2][0]*U[0][1]-U[0][0]*U[2][1];
    U[2][2]=U[0][0]*U[1][1]-U[1][0]*U[0][1];
  }
  float dd=det3f(U)*det3f(V);
  *dsg = (dd>=0.0f)?1.0f:-1.0f;
}

__device__ void proc_bwd(const float dRm[3][3], const float* sv, float dH[3][3])
{
  float U[3][3],V[3][3],s[3],dsg;
  for (int i=0;i<3;i++) for (int j=0;j<3;j++){ U[i][j]=sv[i*3+j]; V[i][j]=sv[12+i*3+j]; }
  s[0]=sv[9]; s[1]=sv[10]; s[2]=sv[11];
  dsg=sv[21];
  float A0[3][3];
  for (int a=0;a<3;a++) for (int c=0;c<3;c++){
    float x=0.0f;
    for (int i=0;i<3;i++) for (int j=0;j<3;j++) x += U[i][a]*dRm[i][j]*V[j][c];
    A0[a][c]=x;
  }
  float D[3]={1.0f,1.0f,dsg};
  float Q[3][3]={{0,0,0},{0,0,0},{0,0,0}};
  for (int i=0;i<3;i++) for (int j=0;j<3;j++){
    if (i==j) continue;
    float Muu=A0[i][j]*D[j]-D[i]*A0[j][i];
    float Mvv=A0[j][i]*D[j]-D[i]*A0[i][j];
    float den=s[j]*s[j]-s[i]*s[i];
    if (fabsf(den)<1e-18f) den=(den>=0.0f?1e-18f:-1e-18f);
    Q[i][j]=(Muu*s[j]+s[i]*Mvv)/den;
  }
  for (int i=0;i<3;i++) for (int j=0;j<3;j++){
    float x=0.0f;
    for (int a=0;a<3;a++) for (int c=0;c<3;c++) x += U[i][a]*Q[a][c]*V[j][c];
    dH[i][j]=x;
  }
}

__device__ void pace_fwd_wave(const float y[3], const float* consts, float* sav,
                              int lane, int save,
                              float R3[3][3], float tvec[3], float cout[Kb])
{
  int n = lane & 31;
  const float* Gi=consts+CD_GI;
  const float* Bmean=consts+CD_BMEAN;
  float wsum=consts[CD_WSUM], lamK=consts[CD_LAMK];
  float wd_n=consts[CD_WD+n];
  float Bc_n[15];
  for (int e=0;e<15;e++) Bc_n[e]=consts[CD_BC+e*Npts+n];

  float ymean[3], yc[3];
  for (int i=0;i<3;i++) ymean[i]=wsum32(y[i]*wd_n)/wsum;
  for (int i=0;i<3;i++) yc[i]=y[i]-ymean[i];
  if (save && lane<32) for (int i=0;i<3;i++) sav[SV_YC+i*Npts+n]=yc[i];

  float c[Kb];
  for (int k=0;k<Kb;k++) c[k]=1.0f/(float)Kb;

  for (int r=0;r<3;r++){
    float bb[3];
    for (int i=0;i<3;i++){
      float a=0.0f;
      for (int k=0;k<Kb;k++) a+=c[k]*Bc_n[k*3+i];
      bb[i]=a;
    }
    float H[3][3];
    for (int i=0;i<3;i++){
      float wy=yc[i]*wd_n;
      for (int j=0;j<3;j++) H[i][j]=wsum32(wy*bb[j]);
    }
    float U[3][3],V[3][3],s[3],dsg;
    svd3f(H,U,s,V,&dsg);
    float R[3][3];
    for (int i=0;i<3;i++) for (int j=0;j<3;j++)
      R[i][j]=U[i][0]*V[j][0]+U[i][1]*V[j][1]+dsg*U[i][2]*V[j][2];

    if (save){
      if (lane<32) for (int i=0;i<3;i++) sav[SV_B1+r*96+i*Npts+n]=bb[i];
      if (lane==0){
        float* pr=sav+SV_R1+r*9;
        for (int i=0;i<3;i++) for (int j=0;j<3;j++) pr[i*3+j]=R[i][j];
        float* pu=sav+SV_U1+r*SV_USTR;
        for (int i=0;i<3;i++) for (int j=0;j<3;j++){ pu[i*3+j]=U[i][j]; pu[12+i*3+j]=V[i][j]; }
        pu[9]=s[0]; pu[10]=s[1]; pu[11]=s[2]; pu[21]=dsg;
      }
    }

    if (r<2){
      float yr[3];
      for (int i=0;i<3;i++) yr[i]=R[0][i]*yc[0]+R[1][i]*yc[1]+R[2][i]*yc[2];
      float h[Kb];
      for (int k=0;k<Kb;k++){
        float p=(Bc_n[k*3+0]*yr[0]+Bc_n[k*3+1]*yr[1]+Bc_n[k*3+2]*yr[2])*wd_n;
        h[k]=wsum32(p)+lamK;
      }
      for (int k=0;k<Kb;k++){
        float a=0.0f;
        for (int l=0;l<Kb;l++) a+=Gi[k*Kb+l]*h[l];
        c[k]=a;
      }
    } else {
      for (int i=0;i<3;i++) for (int j=0;j<3;j++) R3[i][j]=R[i][j];
    }
  }
  float bmean[3];
  for (int i=0;i<3;i++){
    float a=0.0f;
    for (int k=0;k<Kb;k++) a+=c[k]*Bmean[k*3+i];
    bmean[i]=a;
  }
  for (int i=0;i<3;i++)
    tvec[i]=ymean[i]-(R3[i][0]*bmean[0]+R3[i][1]*bmean[1]+R3[i][2]*bmean[2]);
  for (int k=0;k<Kb;k++) cout[k]=c[k];
  if (save && lane==0) for (int k=0;k<Kb;k++) sav[SV_C2+k]=c[k];
}

__device__ void pace_bwd_wave(const float red[17], const float* consts, const float* sav,
                              int lane, float dy[3])
{
  int n = lane & 31;
  const float* Gi=consts+CD_GI;
  const float* Bmean=consts+CD_BMEAN;
  float wsum=consts[CD_WSUM];
  float wd_n=consts[CD_WD+n];
  float Bc_n[15];
  for (int e=0;e<15;e++) Bc_n[e]=consts[CD_BC+e*Npts+n];
  float yc[3], b0v[3], b1v[3], b2v[3];
  for (int i=0;i<3;i++){
    yc[i] =sav[SV_YC+i*Npts+n];
    b0v[i]=sav[SV_B1+0*96+i*Npts+n];
    b1v[i]=sav[SV_B1+1*96+i*Npts+n];
    b2v[i]=sav[SV_B1+2*96+i*Npts+n];
  }
  float c2[Kb];
  for (int k=0;k<Kb;k++) c2[k]=sav[SV_C2+k];
  float R3[3][3];
  for (int i=0;i<3;i++) for (int j=0;j<3;j++) R3[i][j]=sav[SV_R1+18+i*3+j];

  float dt[3]={red[0],red[1],red[2]};
  float dRm[3][3];
  for (int i=0;i<3;i++) for (int j=0;j<3;j++) dRm[i][j]=red[3+i*3+j];
  float dc[Kb];
  for (int k=0;k<Kb;k++) dc[k]=red[12+k];

  float bmean[3];
  for (int i=0;i<3;i++){ float a=0.0f; for (int k=0;k<Kb;k++) a+=c2[k]*Bmean[k*3+i]; bmean[i]=a; }
  for (int i=0;i<3;i++) for (int j=0;j<3;j++) dRm[i][j]-=dt[i]*bmean[j];
  float dbm[3];
  for (int i=0;i<3;i++) dbm[i]=-(R3[0][i]*dt[0]+R3[1][i]*dt[1]+R3[2][i]*dt[2]);
  for (int k=0;k<Kb;k++) dc[k]+=dbm[0]*Bmean[k*3+0]+dbm[1]*Bmean[k*3+1]+dbm[2]*Bmean[k*3+2];

  float dH[3][3];
  proc_bwd(dRm, sav+SV_U1+2*SV_USTR, dH);
  float dyc[3];
  for (int i=0;i<3;i++)
    dyc[i]=wd_n*(dH[i][0]*b2v[0]+dH[i][1]*b2v[1]+dH[i][2]*b2v[2]);
  {
    float dcp[Kb]={0,0,0,0,0};
    for (int j=0;j<3;j++){
      float db=wd_n*(dH[0][j]*yc[0]+dH[1][j]*yc[1]+dH[2][j]*yc[2]);
      for (int k=0;k<Kb;k++) dcp[k]+=db*Bc_n[k*3+j];
    }
    for (int k=0;k<Kb;k++) dc[k]+=wsum32(dcp[k]);
  }
  #pragma unroll
  for (int it=1; it>=0; --it){
    float dh[Kb];
    for (int k=0;k<Kb;k++){ float a=0.0f; for (int l=0;l<Kb;l++) a+=Gi[k*Kb+l]*dc[l]; dh[k]=a; }
    float dyr[3];
    for (int i=0;i<3;i++){
      float a=0.0f;
      for (int k=0;k<Kb;k++) a+=dh[k]*Bc_n[k*3+i];
      dyr[i]=wd_n*a;
    }
    float dR2[3][3];
    for (int j=0;j<3;j++) for (int i=0;i<3;i++) dR2[j][i]=wsum32(yc[j]*dyr[i]);
    float Rr[9];
    for (int e=0;e<9;e++) Rr[e]=sav[SV_R1+it*9+e];
    for (int j=0;j<3;j++) dyc[j]+=Rr[j*3+0]*dyr[0]+Rr[j*3+1]*dyr[1]+Rr[j*3+2]*dyr[2];
    proc_bwd(dR2, sav+SV_U1+it*SV_USTR, dH);
    float bs0,bs1,bs2;
    if (it==1){ bs0=b1v[0]; bs1=b1v[1]; bs2=b1v[2]; }
    else      { bs0=b0v[0]; bs1=b0v[1]; bs2=b0v[2]; }
    for (int i=0;i<3;i++) dyc[i]+=wd_n*(dH[i][0]*bs0+dH[i][1]*bs1+dH[i][2]*bs2);
    if (it>0){
      float dcp[Kb]={0,0,0,0,0};
      for (int j=0;j<3;j++){
        float db=wd_n*(dH[0][j]*yc[0]+dH[1][j]*yc[1]+dH[2][j]*yc[2]);
        for (int k=0;k<Kb;k++) dcp[k]+=db*Bc_n[k*3+j];
      }
      for (int k=0;k<Kb;k++) dc[k]=wsum32(dcp[k]);
    }
  }
  for (int i=0;i<3;i++){
    float S=wsum32(dyc[i]);
    dy[i]=dyc[i]+wd_n/wsum*(dt[i]-S);
  }
}

// fp64 consts, static pivot-free GJ (G is SPD + lam ridge) -> all registers
__device__ void compute_consts_static(const float* mkp, const float* w, const float* lamp,
                                      int lane, float* cl)
{
  int n=lane&31;
  double wv=(double)w[n];
  double wsum=dsum32(wv);
  double mk[15], Bm[15], Bc_n[15];
  #pragma unroll
  for (int e=0;e<15;e++) mk[e]=(double)mkp[e*Npts+n];
  #pragma unroll
  for (int e=0;e<15;e++) Bm[e]=dsum32(mk[e]*wv)/wsum;
  #pragma unroll
  for (int e=0;e<15;e++) Bc_n[e]=mk[e]-Bm[e];
  double lam=(double)lamp[0];
  double G[Kb][Kb], GI[Kb][Kb];
  #pragma unroll
  for (int k=0;k<Kb;k++)
  #pragma unroll
  for (int l=0;l<Kb;l++){
    double p=(Bc_n[k*3+0]*Bc_n[l*3+0]+Bc_n[k*3+1]*Bc_n[l*3+1]+Bc_n[k*3+2]*Bc_n[l*3+2])*wv;
    G[k][l]=dsum32(p)+((k==l)?lam:0.0);
    GI[k][l]=(k==l)?1.0:0.0;
  }
  #pragma unroll
  for (int col=0;col<Kb;col++){
    double ip=1.0/G[col][col];
    #pragma unroll
    for (int j=0;j<Kb;j++){ G[col][j]*=ip; GI[col][j]*=ip; }
    #pragma unroll
    for (int r=0;r<Kb;r++){
      if (r==col) continue;
      double f=G[r][col];
      #pragma unroll
      for (int j=0;j<Kb;j++){ G[r][j]-=f*G[col][j]; GI[r][j]-=f*GI[col][j]; }
    }
  }
  if (lane<32){
    cl[CD_WD+n]=(float)wv;
    #pragma unroll
    for (int e=0;e<15;e++) cl[CD_BC+e*Npts+n]=(float)Bc_n[e];
  }
  if (lane==0){
    cl[CD_WSUM]=(float)wsum;
    cl[CD_LAMK]=(float)(lam/(double)Kb);
    #pragma unroll
    for (int e=0;e<15;e++) cl[CD_BMEAN+e]=(float)Bm[e];
    #pragma unroll
    for (int k=0;k<Kb;k++)
    #pragma unroll
    for (int l=0;l<Kb;l++) cl[CD_GI+k*Kb+l]=(float)GI[k][l];
  }
}

// ---------------- kernels ----------------
__global__ void k_init(const float* __restrict__ kp, const float* __restrict__ corr0,
                       const float* __restrict__ mkp, const float* __restrict__ w,
                       const float* __restrict__ lamp,
                       float* __restrict__ consts, float* __restrict__ posebuf,
                       float* __restrict__ corrbuf, float* __restrict__ savbuf)
{
  int b=blockIdx.x, lane=threadIdx.x, n=lane&31;
  __shared__ float cl[560];
  compute_consts_static(mkp, w, lamp, lane, cl);
  for (int e=lane;e<96;e+=64) corrbuf[b*96+e]=corr0[b*96+e];
  float y[3];
  for (int i=0;i<3;i++) y[i]=kp[b*96+i*Npts+n]+corr0[b*96+i*Npts+n];
  float R3[3][3],tv[3],cc[Kb];
  pace_fwd_wave(y, cl, savbuf+(size_t)b*512, lane, 1, R3, tv, cc);
  if (lane==0){
    float* P=posebuf+b*20;
    for (int i=0;i<3;i++){ P[9+i]=tv[i]; for (int j=0;j<3;j++) P[i*3+j]=R3[i][j]; }
    for (int k=0;k<Kb;k++) P[12+k]=cc[k];
  }
  if (b==0) for (int e=lane;e<560;e+=64) consts[e]=cl[e];
}

// k_step: 256 blocks x 512 thr. [s>0: redundant PACE update] + chamfer (4 pts/thread,
// prefetch-pipelined LDS reads, DPP combines) + 17-sum via DPP
__global__ __launch_bounds__(512,1) void k_step(const float* __restrict__ pc,
    const float* __restrict__ kp, const float* __restrict__ cad,
    const float* __restrict__ consts, const float* __restrict__ posebuf,
    float* __restrict__ corrbuf, float* __restrict__ savbuf,
    float* __restrict__ accbuf, int step)
{
  int blk=blockIdx.x;
  int b=blk>>5, chunk=blk&31;
  int tid=threadIdx.x;
  __shared__ float4 smod[NCAD];
  __shared__ float s_cl[560];
  __shared__ float s_sav[512];
  __shared__ float s_pose[20];
  __shared__ float s_part[8][17];

  int wsel=step&1, rsel=1-wsel;
  float* acc_w = accbuf + (size_t)wsel*(Bsz*NCHUNK*20);
  const float* acc_r = accbuf + (size_t)rsel*(Bsz*NCHUNK*20);
  const float* corr_r = corrbuf + rsel*(Bsz*96) + b*96;
  float* corr_w = corrbuf + wsel*(Bsz*96) + b*96;
  const float* sav_r = savbuf + (size_t)rsel*(Bsz*512) + b*512;
  float* sav_w = savbuf + (size_t)wsel*(Bsz*512) + b*512;

  if (tid<64){
    int lane=tid, n=lane&31;
    for (int e=lane;e<560;e+=64) s_cl[e]=consts[e];
    if (step==0){
      if (lane<20) s_pose[lane]=posebuf[b*20+lane];
    } else {
      for (int e=lane;e<512;e+=64) s_sav[e]=sav_r[e];
      float red[17];
      if (lane<17){
        float a=0.f;
        for (int ch=0;ch<NCHUNK;ch++) a+=acc_r[(b*NCHUNK+ch)*20+lane];
        s_part[0][lane]=a*(2.0f/(float)Mpc);
      }
      for (int v=0;v<17;v++) red[v]=s_part[0][v];
      float dy[3];
      pace_bwd_wave(red, s_cl, s_sav, lane, dy);
      float newc[3];
      for (int i=0;i<3;i++) newc[i]=corr_r[i*Npts+n]-0.5f*dy[i];
      float y[3];
      for (int i=0;i<3;i++) y[i]=kp[b*96+i*Npts+n]+newc[i];
      float R3[3][3],tv[3],cc[Kb];
      pace_fwd_wave(y, s_cl, s_sav, lane, 1, R3, tv, cc);
      if (lane==0){
        for (int i=0;i<3;i++){ s_pose[9+i]=tv[i]; for (int j=0;j<3;j++) s_pose[i*3+j]=R3[i][j]; }
        for (int k=0;k<Kb;k++) s_pose[12+k]=cc[k];
      }
      if (chunk==0){
        if (lane<32) for (int i=0;i<3;i++) corr_w[i*Npts+n]=newc[i];
        for (int e=lane;e<512;e+=64) sav_w[e]=s_sav[e];
      }
    }
  }
  __syncthreads();

  float R[9],T[3],C[Kb];
  for (int e=0;e<9;e++) R[e]=s_pose[e];
  for (int i=0;i<3;i++) T[i]=s_pose[9+i];
  for (int k=0;k<Kb;k++) C[k]=s_pose[12+k];
  // build rotated model + |.|^2 into LDS (4 j per thread)
  for (int j=tid;j<NCAD;j+=512){
    float cv[15];
    for (int e=0;e<15;e++) cv[e]=cad[e*NCAD+j];
    float m0=0.f,m1=0.f,m2=0.f;
    for (int k=0;k<Kb;k++){ m0+=C[k]*cv[k*3+0]; m1+=C[k]*cv[k*3+1]; m2+=C[k]*cv[k*3+2]; }
    float ax=R[0]*m0+R[1]*m1+R[2]*m2+T[0];
    float ay=R[3]*m0+R[4]*m1+R[5]*m2+T[1];
    float az=R[6]*m0+R[7]*m1+R[8]*m2+T[2];
    smod[j]=make_float4(ax,ay,az, ax*ax+ay*ay+az*az);
  }
  __syncthreads();
  // argmin: 4 points/thread, 16 threads/point-group (j stride 16), explicit prefetch pipeline
  int pr=tid>>4, q=tid&15;
  int pbase=chunk*PPB+pr*4;
  const float* pcb=pc+(size_t)b*3*Mpc;
  float px0=pcb[pbase+0],       px1=pcb[pbase+1],       px2=pcb[pbase+2],       px3=pcb[pbase+3];
  float py0=pcb[Mpc+pbase+0],   py1=pcb[Mpc+pbase+1],   py2=pcb[Mpc+pbase+2],   py3=pcb[Mpc+pbase+3];
  float pz0=pcb[2*Mpc+pbase+0], pz1=pcb[2*Mpc+pbase+1], pz2=pcb[2*Mpc+pbase+2], pz3=pcb[2*Mpc+pbase+3];
  float nx0=-2.f*px0, nx1=-2.f*px1, nx2=-2.f*px2, nx3=-2.f*px3;
  float ny0=-2.f*py0, ny1=-2.f*py1, ny2=-2.f*py2, ny3=-2.f*py3;
  float nz0=-2.f*pz0, nz1=-2.f*pz1, nz2=-2.f*pz2, nz3=-2.f*pz3;
  float d0=3.4e38f, d1=3.4e38f, d2=3.4e38f, d3=3.4e38f;
  int j0=0, j1=0, j2=0, j3=0;
  float4 mcur=smod[q];
  int jc=q;
  #pragma unroll 8
  for (int it=0; it<NCAD/16-1; ++it){
    float4 mnext=smod[jc+16];           // prefetch next tile under current compute
    float c;
    c=fmaf(nx0,mcur.x,fmaf(ny0,mcur.y,fmaf(nz0,mcur.z,mcur.w))); if(c<d0){d0=c;j0=jc;}
    c=fmaf(nx1,mcur.x,fmaf(ny1,mcur.y,fmaf(nz1,mcur.z,mcur.w))); if(c<d1){d1=c;j1=jc;}
    c=fmaf(nx2,mcur.x,fmaf(ny2,mcur.y,fmaf(nz2,mcur.z,mcur.w))); if(c<d2){d2=c;j2=jc;}
    c=fmaf(nx3,mcur.x,fmaf(ny3,mcur.y,fmaf(nz3,mcur.z,mcur.w))); if(c<d3){d3=c;j3=jc;}
    mcur=mnext; jc+=16;
  }
  {
    float c;
    c=fmaf(nx0,mcur.x,fmaf(ny0,mcur.y,fmaf(nz0,mcur.z,mcur.w))); if(c<d0){d0=c;j0=jc;}
    c=fmaf(nx1,mcur.x,fmaf(ny1,mcur.y,fmaf(nz1,mcur.z,mcur.w))); if(c<d1){d1=c;j1=jc;}
    c=fmaf(nx2,mcur.x,fmaf(ny2,mcur.y,fmaf(nz2,mcur.z,mcur.w))); if(c<d2){d2=c;j2=jc;}
    c=fmaf(nx3,mcur.x,fmaf(ny3,mcur.y,fmaf(nz3,mcur.z,mcur.w))); if(c<d3){d3=c;j3=jc;}
  }
  // combine within 16-lane groups via DPP (xor1, xor2, then half_mirror==xor4, mirror==xor8
  // once sub-groups are uniform); smaller j wins ties
  #define DPPMIN(dd,jj,ctrl) { \
    float od=__int_as_float(__builtin_amdgcn_update_dpp(0,__float_as_int(dd),ctrl,0xf,0xf,true)); \
    int   oj=__builtin_amdgcn_update_dpp(0,jj,ctrl,0xf,0xf,true); \
    if(od<dd||(od==dd&&oj<jj)){dd=od;jj=oj;} }
  DPPMIN(d0,j0,0xB1) DPPMIN(d0,j0,0x4E) DPPMIN(d0,j0,0x141) DPPMIN(d0,j0,0x140)
  DPPMIN(d1,j1,0xB1) DPPMIN(d1,j1,0x4E) DPPMIN(d1,j1,0x141) DPPMIN(d1,j1,0x140)
  DPPMIN(d2,j2,0xB1) DPPMIN(d2,j2,0x4E) DPPMIN(d2,j2,0x141) DPPMIN(d2,j2,0x140)
  DPPMIN(d3,j3,0xB1) DPPMIN(d3,j3,0x4E) DPPMIN(d3,j3,0x141) DPPMIN(d3,j3,0x140)
  #undef DPPMIN
  // per-point gradient -> 17 partial sums (lanes q<4 own point pbase+q)
  float vals[17];
  for (int v=0;v<17;v++) vals[v]=0.f;
  if (q<4){
    float selx=(q==0)?px0:(q==1)?px1:(q==2)?px2:px3;
    float sely=(q==0)?py0:(q==1)?py1:(q==2)?py2:py3;
    float selz=(q==0)?pz0:(q==1)?pz1:(q==2)?pz2:pz3;
    int   selj=(q==0)?j0 :(q==1)?j1 :(q==2)?j2 :j3;
    float4 m=smod[selj];
    float md0=m.x-selx, md1=m.y-sely, md2=m.z-selz;
    float cv[15];
    for (int e=0;e<15;e++) cv[e]=cad[e*NCAD+selj];
    float m00=0.f,m01=0.f,m02=0.f;
    for (int k=0;k<Kb;k++){ m00+=C[k]*cv[k*3+0]; m01+=C[k]*cv[k*3+1]; m02+=C[k]*cv[k*3+2]; }
    vals[0]=md0; vals[1]=md1; vals[2]=md2;
    vals[3]=md0*m00; vals[4]=md0*m01; vals[5]=md0*m02;
    vals[6]=md1*m00; vals[7]=md1*m01; vals[8]=md1*m02;
    vals[9]=md2*m00; vals[10]=md2*m01; vals[11]=md2*m02;
    float t0=R[0]*md0+R[3]*md1+R[6]*md2;
    float t1=R[1]*md0+R[4]*md1+R[7]*md2;
    float t2=R[2]*md0+R[5]*md1+R[8]*md2;
    for (int k=0;k<Kb;k++) vals[12+k]=t0*cv[k*3+0]+t1*cv[k*3+1]+t2*cv[k*3+2];
  }
  // full 64-lane sums via DPP, uniform result; lane (tid&63)==0 stores
  for (int v=0;v<17;v++) vals[v]=wsum64(vals[v]);
  int wv=tid>>6;
  if ((tid&63)==0) for (int v=0;v<17;v++) s_part[wv][v]=vals[v];
  __syncthreads();
  if (tid<17){
    float a=0.f;
    for (int w=0;w<8;w++) a+=s_part[w][tid];
    acc_w[(b*NCHUNK+chunk)*20+tid]=a;
  }
}

// k_fin: update #20 + final PACE fwd -> outputs. 8 blocks x 64 thr.
__global__ void k_fin(const float* __restrict__ kp, const float* __restrict__ consts,
                      const float* __restrict__ corrbuf, const float* __restrict__ savbuf,
                      const float* __restrict__ accbuf, float* __restrict__ out)
{
  int b=blockIdx.x, lane=threadIdx.x, n=lane&31;
  // step==NSTEPS(20): rsel = 1-(20&1) = 1
  const float* acc_r = accbuf + (size_t)1*(Bsz*NCHUNK*20);
  const float* corr_r = corrbuf + 1*(Bsz*96) + b*96;
  const float* sav_r = savbuf + (size_t)1*(Bsz*512) + b*512;
  __shared__ float s_cl[560];
  __shared__ float s_sav[512];
  __shared__ float s_red[17];
  for (int e=lane;e<560;e+=64) s_cl[e]=consts[e];
  for (int e=lane;e<512;e+=64) s_sav[e]=sav_r[e];
  if (lane<17){
    float a=0.f;
    for (int ch=0;ch<NCHUNK;ch++) a+=acc_r[(b*NCHUNK+ch)*20+lane];
    s_red[lane]=a*(2.0f/(float)Mpc);
  }
  __syncthreads();
  float red[17];
  for (int v=0;v<17;v++) red[v]=s_red[v];
  float dy[3];
  pace_bwd_wave(red, s_cl, s_sav, lane, dy);
  float newc[3];
  for (int i=0;i<3;i++) newc[i]=corr_r[i*Npts+n]-0.5f*dy[i];
  float y[3];
  for (int i=0;i<3;i++) y[i]=kp[b*96+i*Npts+n]+newc[i];
  float R3[3][3],tv[3],cc[Kb];
  pace_fwd_wave(y, s_cl, s_sav, lane, 0, R3, tv, cc);
  if (lane==0){
    for (int i=0;i<3;i++) for (int j=0;j<3;j++) out[b*9+i*3+j]=R3[i][j];
    for (int i=0;i<3;i++) out[72+b*3+i]=tv[i];
    for (int k=0;k<Kb;k++) out[96+b*Kb+k]=cc[k];
  }
  if (lane<32){
    for (int i=0;i<3;i++){
      out[136+b*96+i*Npts+n]=newc[i];
      out[904+b*96+i*Npts+n]=kp[b*96+i*Npts+n]+newc[i];
    }
  }
}

extern "C" void kernel_launch(void* const* d_in, const int* in_sizes, int n_in,
                              void* d_out, int out_size, void* d_ws, size_t ws_size,
                              hipStream_t stream) {
  const float* pc   =(const float*)d_in[0];
  const float* kp   =(const float*)d_in[1];
  const float* corr0=(const float*)d_in[2];
  const float* mkp  =(const float*)d_in[3];
  const float* cad  =(const float*)d_in[4];
  const float* w    =(const float*)d_in[5];
  const float* lam  =(const float*)d_in[6];
  float* out=(float*)d_out;
  char* ws=(char*)d_ws;
  float* consts =(float*)(ws+0);        // 560
  float* posebuf=(float*)(ws+4096);     // 160
  float* corrbuf=(float*)(ws+8192);     // 2*768
  float* savbuf =(float*)(ws+16384);    // 2*4096
  float* accbuf =(float*)(ws+49152);    // 2*5120

  hipLaunchKernelGGL(k_init, dim3(Bsz), dim3(64), 0, stream,
                     kp, corr0, mkp, w, lam, consts, posebuf, corrbuf, savbuf);
  for (int s=0; s<NSTEPS; ++s){
    hipLaunchKernelGGL(k_step, dim3(Bsz*NCHUNK), dim3(512), 0, stream,
                       pc, kp, cad, consts, posebuf, corrbuf, savbuf, accbuf, s);
  }
  hipLaunchKernelGGL(k_fin, dim3(Bsz), dim3(64), 0, stream,
                     kp, consts, corrbuf, savbuf, accbuf, out);
}

// Round 15
// 747.196 us; speedup vs baseline: 1.1259x; 1.0487x over previous
//
#include <hip/hip_runtime.h>

#define Bsz 8
#define Npts 32
#define Kb 5
#define Mpc 4096
#define NCAD 2048
#define NSTEPS 20
#define NCHUNK 32
#define PPB 128

// consts layout
#define CD_GI 0
#define CD_BMEAN 25
#define CD_WD 40
#define CD_WSUM 72
#define CD_LAMK 74
#define CD_BC 80
// sav layout
#define SV_YC 0
#define SV_B1 96
#define SV_R1 384
#define SV_U1 411
#define SV_C2 477
#define SV_USTR 22

// ---------- fast hw math (v_rcp_f32 / v_rsq_f32 / v_sqrt_f32, ~1 ULP) ----------
__device__ __forceinline__ float frcp(float x){ return __builtin_amdgcn_rcpf(x); }
__device__ __forceinline__ float frsq(float x){ return __builtin_amdgcn_rsqf(x); }
__device__ __forceinline__ float fsqrt(float x){ return __builtin_amdgcn_sqrtf(x); }

// ---------- DPP-based wave reductions ----------
template<int CTRL,int RM,bool BC>
__device__ __forceinline__ float fdpp_add(float v){
  int t=__builtin_amdgcn_update_dpp(0, __float_as_int(v), CTRL, RM, 0xf, BC);
  return v+__int_as_float(t);
}
__device__ __forceinline__ float wsum64(float v){
  v=fdpp_add<0xB1,0xf,true>(v);
  v=fdpp_add<0x4E,0xf,true>(v);
  v=fdpp_add<0x141,0xf,true>(v);
  v=fdpp_add<0x140,0xf,true>(v);
  v=fdpp_add<0x142,0xa,false>(v);
  v=fdpp_add<0x143,0xc,false>(v);
  return __int_as_float(__builtin_amdgcn_readlane(__float_as_int(v),63));
}
__device__ __forceinline__ float wsum32(float v){ return 0.5f*wsum64(v); }

template<int CTRL,int RM,bool BC>
__device__ __forceinline__ double ddpp_add(double v){
  int lo=__builtin_amdgcn_update_dpp(0, __double2loint(v), CTRL, RM, 0xf, BC);
  int hi=__builtin_amdgcn_update_dpp(0, __double2hiint(v), CTRL, RM, 0xf, BC);
  return v+__hiloint2double(hi,lo);
}
__device__ __forceinline__ double dsum32(double v){
  v=ddpp_add<0xB1,0xf,true>(v);
  v=ddpp_add<0x4E,0xf,true>(v);
  v=ddpp_add<0x141,0xf,true>(v);
  v=ddpp_add<0x140,0xf,true>(v);
  v=ddpp_add<0x142,0xa,false>(v);
  v=ddpp_add<0x143,0xc,false>(v);
  int lo=__builtin_amdgcn_readlane(__double2loint(v),63);
  int hi=__builtin_amdgcn_readlane(__double2hiint(v),63);
  return 0.5*__hiloint2double(hi,lo);
}

__device__ __forceinline__ float det3f(const float M[3][3]){
  return M[0][0]*(M[1][1]*M[2][2]-M[1][2]*M[2][1])
       - M[0][1]*(M[1][0]*M[2][2]-M[1][2]*M[2][0])
       + M[0][2]*(M[1][0]*M[2][1]-M[1][1]*M[2][0]);
}

#define JROTF(p,q,u) { \
  float apq=A[p][q]; \
  if (fabsf(apq)>1e-30f){ \
    float theta=(A[q][q]-A[p][p])*0.5f*frcp(apq); \
    float tt=(theta>=0.0f)?frcp(theta+fsqrt(1.0f+theta*theta)):frcp(theta-fsqrt(1.0f+theta*theta)); \
    float cc=frsq(1.0f+tt*tt), ssn=tt*cc; \
    float app=A[p][p], aqq=A[q][q]; \
    A[p][p]=app-tt*apq; A[q][q]=aqq+tt*apq; A[p][q]=0.0f; A[q][p]=0.0f; \
    float aup=A[u][p], auq=A[u][q]; \
    A[u][p]=cc*aup-ssn*auq; A[p][u]=A[u][p]; \
    A[u][q]=ssn*aup+cc*auq; A[q][u]=A[u][q]; \
    for (int i_=0;i_<3;i_++){ float vip=V[i_][p], viq=V[i_][q]; V[i_][p]=cc*vip-ssn*viq; V[i_][q]=ssn*vip+cc*viq; } \
  } }

__device__ void svd3f(const float H[3][3], float U[3][3], float s[3], float V[3][3], float* dsg)
{
  float A[3][3];
  for (int i=0;i<3;i++) for (int j=0;j<3;j++){
    float a=0.0f;
    for (int k=0;k<3;k++) a += H[k][i]*H[k][j];
    A[i][j]=a;
  }
  V[0][0]=1;V[0][1]=0;V[0][2]=0; V[1][0]=0;V[1][1]=1;V[1][2]=0; V[2][0]=0;V[2][1]=0;V[2][2]=1;
  for (int sweep=0; sweep<6; ++sweep){
    float off=fabsf(A[0][1])+fabsf(A[0][2])+fabsf(A[1][2]);
    float dia=fabsf(A[0][0])+fabsf(A[1][1])+fabsf(A[2][2]);
    if (off <= 3e-7f*dia + 1e-30f) break;
    JROTF(0,1,2)
    JROTF(0,2,1)
    JROTF(1,2,0)
  }
  float e0=A[0][0], e1=A[1][1], e2=A[2][2];
  if (e0<e1){ float t=e0;e0=e1;e1=t; for(int i=0;i<3;i++){float tv=V[i][0];V[i][0]=V[i][1];V[i][1]=tv;} }
  if (e0<e2){ float t=e0;e0=e2;e2=t; for(int i=0;i<3;i++){float tv=V[i][0];V[i][0]=V[i][2];V[i][2]=tv;} }
  if (e1<e2){ float t=e1;e1=e2;e2=t; for(int i=0;i<3;i++){float tv=V[i][1];V[i][1]=V[i][2];V[i][2]=tv;} }
  for (int c=0;c<3;c++){
    float u0=H[0][0]*V[0][c]+H[0][1]*V[1][c]+H[0][2]*V[2][c];
    float u1=H[1][0]*V[0][c]+H[1][1]*V[1][c]+H[1][2]*V[2][c];
    float u2=H[2][0]*V[0][c]+H[2][1]*V[1][c]+H[2][2]*V[2][c];
    float nr=fsqrt(u0*u0+u1*u1+u2*u2);
    s[c]=nr;
    float inv=(nr>1e-30f)?frcp(nr):0.0f;
    U[0][c]=u0*inv; U[1][c]=u1*inv; U[2][c]=u2*inv;
  }
  if (s[2] <= 1e-6f*s[0]){
    U[0][2]=U[1][0]*U[2][1]-U[2][0]*U[1][1];
    U[1][2]=U[2][0]*U[0][1]-U[0][0]*U[2][1];
    U[2][2]=U[0][0]*U[1][1]-U[1][0]*U[0][1];
  }
  float dd=det3f(U)*det3f(V);
  *dsg = (dd>=0.0f)?1.0f:-1.0f;
}

__device__ void proc_bwd(const float dRm[3][3], const float* sv, float dH[3][3])
{
  float U[3][3],V[3][3],s[3],dsg;
  for (int i=0;i<3;i++) for (int j=0;j<3;j++){ U[i][j]=sv[i*3+j]; V[i][j]=sv[12+i*3+j]; }
  s[0]=sv[9]; s[1]=sv[10]; s[2]=sv[11];
  dsg=sv[21];
  float A0[3][3];
  for (int a=0;a<3;a++) for (int c=0;c<3;c++){
    float x=0.0f;
    for (int i=0;i<3;i++) for (int j=0;j<3;j++) x += U[i][a]*dRm[i][j]*V[j][c];
    A0[a][c]=x;
  }
  float D[3]={1.0f,1.0f,dsg};
  float Q[3][3]={{0,0,0},{0,0,0},{0,0,0}};
  for (int i=0;i<3;i++) for (int j=0;j<3;j++){
    if (i==j) continue;
    float Muu=A0[i][j]*D[j]-D[i]*A0[j][i];
    float Mvv=A0[j][i]*D[j]-D[i]*A0[i][j];
    float den=s[j]*s[j]-s[i]*s[i];
    if (fabsf(den)<1e-18f) den=(den>=0.0f?1e-18f:-1e-18f);
    Q[i][j]=(Muu*s[j]+s[i]*Mvv)*frcp(den);
  }
  for (int i=0;i<3;i++) for (int j=0;j<3;j++){
    float x=0.0f;
    for (int a=0;a<3;a++) for (int c=0;c<3;c++) x += U[i][a]*Q[a][c]*V[j][c];
    dH[i][j]=x;
  }
}

__device__ void pace_fwd_wave(const float y[3], const float* consts, float* sav,
                              int lane, int save,
                              float R3[3][3], float tvec[3], float cout[Kb])
{
  int n = lane & 31;
  const float* Gi=consts+CD_GI;
  const float* Bmean=consts+CD_BMEAN;
  float wsum=consts[CD_WSUM], lamK=consts[CD_LAMK];
  float iws=frcp(wsum);
  float wd_n=consts[CD_WD+n];
  float Bc_n[15];
  for (int e=0;e<15;e++) Bc_n[e]=consts[CD_BC+e*Npts+n];

  float ymean[3], yc[3];
  for (int i=0;i<3;i++) ymean[i]=wsum32(y[i]*wd_n)*iws;
  for (int i=0;i<3;i++) yc[i]=y[i]-ymean[i];
  if (save && lane<32) for (int i=0;i<3;i++) sav[SV_YC+i*Npts+n]=yc[i];

  float c[Kb];
  for (int k=0;k<Kb;k++) c[k]=1.0f/(float)Kb;

  #pragma clang loop unroll(disable)
  for (int r=0;r<3;r++){
    float bb[3];
    for (int i=0;i<3;i++){
      float a=0.0f;
      for (int k=0;k<Kb;k++) a+=c[k]*Bc_n[k*3+i];
      bb[i]=a;
    }
    float H[3][3];
    for (int i=0;i<3;i++){
      float wy=yc[i]*wd_n;
      for (int j=0;j<3;j++) H[i][j]=wsum32(wy*bb[j]);
    }
    float U[3][3],V[3][3],s[3],dsg;
    svd3f(H,U,s,V,&dsg);
    float R[3][3];
    for (int i=0;i<3;i++) for (int j=0;j<3;j++)
      R[i][j]=U[i][0]*V[j][0]+U[i][1]*V[j][1]+dsg*U[i][2]*V[j][2];

    if (save){
      if (lane<32) for (int i=0;i<3;i++) sav[SV_B1+r*96+i*Npts+n]=bb[i];
      if (lane==0){
        float* pr=sav+SV_R1+r*9;
        for (int i=0;i<3;i++) for (int j=0;j<3;j++) pr[i*3+j]=R[i][j];
        float* pu=sav+SV_U1+r*SV_USTR;
        for (int i=0;i<3;i++) for (int j=0;j<3;j++){ pu[i*3+j]=U[i][j]; pu[12+i*3+j]=V[i][j]; }
        pu[9]=s[0]; pu[10]=s[1]; pu[11]=s[2]; pu[21]=dsg;
      }
    }

    if (r<2){
      float yr[3];
      for (int i=0;i<3;i++) yr[i]=R[0][i]*yc[0]+R[1][i]*yc[1]+R[2][i]*yc[2];
      float h[Kb];
      for (int k=0;k<Kb;k++){
        float p=(Bc_n[k*3+0]*yr[0]+Bc_n[k*3+1]*yr[1]+Bc_n[k*3+2]*yr[2])*wd_n;
        h[k]=wsum32(p)+lamK;
      }
      for (int k=0;k<Kb;k++){
        float a=0.0f;
        for (int l=0;l<Kb;l++) a+=Gi[k*Kb+l]*h[l];
        c[k]=a;
      }
    } else {
      for (int i=0;i<3;i++) for (int j=0;j<3;j++) R3[i][j]=R[i][j];
    }
  }
  float bmean[3];
  for (int i=0;i<3;i++){
    float a=0.0f;
    for (int k=0;k<Kb;k++) a+=c[k]*Bmean[k*3+i];
    bmean[i]=a;
  }
  for (int i=0;i<3;i++)
    tvec[i]=ymean[i]-(R3[i][0]*bmean[0]+R3[i][1]*bmean[1]+R3[i][2]*bmean[2]);
  for (int k=0;k<Kb;k++) cout[k]=c[k];
  if (save && lane==0) for (int k=0;k<Kb;k++) sav[SV_C2+k]=c[k];
}

__device__ void pace_bwd_wave(const float red[17], const float* consts, const float* sav,
                              int lane, float dy[3])
{
  int n = lane & 31;
  const float* Gi=consts+CD_GI;
  const float* Bmean=consts+CD_BMEAN;
  float wsum=consts[CD_WSUM];
  float iws=frcp(wsum);
  float wd_n=consts[CD_WD+n];
  float Bc_n[15];
  for (int e=0;e<15;e++) Bc_n[e]=consts[CD_BC+e*Npts+n];
  float yc[3], b0v[3], b1v[3], b2v[3];
  for (int i=0;i<3;i++){
    yc[i] =sav[SV_YC+i*Npts+n];
    b0v[i]=sav[SV_B1+0*96+i*Npts+n];
    b1v[i]=sav[SV_B1+1*96+i*Npts+n];
    b2v[i]=sav[SV_B1+2*96+i*Npts+n];
  }
  float c2[Kb];
  for (int k=0;k<Kb;k++) c2[k]=sav[SV_C2+k];
  float R3[3][3];
  for (int i=0;i<3;i++) for (int j=0;j<3;j++) R3[i][j]=sav[SV_R1+18+i*3+j];

  float dt[3]={red[0],red[1],red[2]};
  float dRm[3][3];
  for (int i=0;i<3;i++) for (int j=0;j<3;j++) dRm[i][j]=red[3+i*3+j];
  float dc[Kb];
  for (int k=0;k<Kb;k++) dc[k]=red[12+k];

  float bmean[3];
  for (int i=0;i<3;i++){ float a=0.0f; for (int k=0;k<Kb;k++) a+=c2[k]*Bmean[k*3+i]; bmean[i]=a; }
  for (int i=0;i<3;i++) for (int j=0;j<3;j++) dRm[i][j]-=dt[i]*bmean[j];
  float dbm[3];
  for (int i=0;i<3;i++) dbm[i]=-(R3[0][i]*dt[0]+R3[1][i]*dt[1]+R3[2][i]*dt[2]);
  for (int k=0;k<Kb;k++) dc[k]+=dbm[0]*Bmean[k*3+0]+dbm[1]*Bmean[k*3+1]+dbm[2]*Bmean[k*3+2];

  float dH[3][3];
  proc_bwd(dRm, sav+SV_U1+2*SV_USTR, dH);
  float dyc[3];
  for (int i=0;i<3;i++)
    dyc[i]=wd_n*(dH[i][0]*b0v[0]*0.0f+dH[i][0]*b2v[0]+dH[i][1]*b2v[1]+dH[i][2]*b2v[2]);
  {
    float dcp[Kb]={0,0,0,0,0};
    for (int j=0;j<3;j++){
      float db=wd_n*(dH[0][j]*yc[0]+dH[1][j]*yc[1]+dH[2][j]*yc[2]);
      for (int k=0;k<Kb;k++) dcp[k]+=db*Bc_n[k*3+j];
    }
    for (int k=0;k<Kb;k++) dc[k]+=wsum32(dcp[k]);
  }
  #pragma clang loop unroll(disable)
  for (int it=1; it>=0; --it){
    float dh[Kb];
    for (int k=0;k<Kb;k++){ float a=0.0f; for (int l=0;l<Kb;l++) a+=Gi[k*Kb+l]*dc[l]; dh[k]=a; }
    float dyr[3];
    for (int i=0;i<3;i++){
      float a=0.0f;
      for (int k=0;k<Kb;k++) a+=dh[k]*Bc_n[k*3+i];
      dyr[i]=wd_n*a;
    }
    float dR2[3][3];
    for (int j=0;j<3;j++) for (int i=0;i<3;i++) dR2[j][i]=wsum32(yc[j]*dyr[i]);
    float Rr[9];
    for (int e=0;e<9;e++) Rr[e]=sav[SV_R1+it*9+e];
    for (int j=0;j<3;j++) dyc[j]+=Rr[j*3+0]*dyr[0]+Rr[j*3+1]*dyr[1]+Rr[j*3+2]*dyr[2];
    proc_bwd(dR2, sav+SV_U1+it*SV_USTR, dH);
    float bs0,bs1,bs2;
    if (it==1){ bs0=b1v[0]; bs1=b1v[1]; bs2=b1v[2]; }
    else      { bs0=b0v[0]; bs1=b0v[1]; bs2=b0v[2]; }
    for (int i=0;i<3;i++) dyc[i]+=wd_n*(dH[i][0]*bs0+dH[i][1]*bs1+dH[i][2]*bs2);
    if (it>0){
      float dcp[Kb]={0,0,0,0,0};
      for (int j=0;j<3;j++){
        float db=wd_n*(dH[0][j]*yc[0]+dH[1][j]*yc[1]+dH[2][j]*yc[2]);
        for (int k=0;k<Kb;k++) dcp[k]+=db*Bc_n[k*3+j];
      }
      for (int k=0;k<Kb;k++) dc[k]=wsum32(dcp[k]);
    }
  }
  for (int i=0;i<3;i++){
    float S=wsum32(dyc[i]);
    dy[i]=dyc[i]+wd_n*iws*(dt[i]-S);
  }
}

// fp64 consts, static pivot-free GJ -> registers
__device__ void compute_consts_static(const float* mkp, const float* w, const float* lamp,
                                      int lane, float* cl)
{
  int n=lane&31;
  double wv=(double)w[n];
  double wsum=dsum32(wv);
  double mk[15], Bm[15], Bc_n[15];
  #pragma unroll
  for (int e=0;e<15;e++) mk[e]=(double)mkp[e*Npts+n];
  #pragma unroll
  for (int e=0;e<15;e++) Bm[e]=dsum32(mk[e]*wv)/wsum;
  #pragma unroll
  for (int e=0;e<15;e++) Bc_n[e]=mk[e]-Bm[e];
  double lam=(double)lamp[0];
  double G[Kb][Kb], GI[Kb][Kb];
  #pragma unroll
  for (int k=0;k<Kb;k++)
  #pragma unroll
  for (int l=0;l<Kb;l++){
    double p=(Bc_n[k*3+0]*Bc_n[l*3+0]+Bc_n[k*3+1]*Bc_n[l*3+1]+Bc_n[k*3+2]*Bc_n[l*3+2])*wv;
    G[k][l]=dsum32(p)+((k==l)?lam:0.0);
    GI[k][l]=(k==l)?1.0:0.0;
  }
  #pragma unroll
  for (int col=0;col<Kb;col++){
    double ip=1.0/G[col][col];
    #pragma unroll
    for (int j=0;j<Kb;j++){ G[col][j]*=ip; GI[col][j]*=ip; }
    #pragma unroll
    for (int r=0;r<Kb;r++){
      if (r==col) continue;
      double f=G[r][col];
      #pragma unroll
      for (int j=0;j<Kb;j++){ G[r][j]-=f*G[col][j]; GI[r][j]-=f*GI[col][j]; }
    }
  }
  if (lane<32){
    cl[CD_WD+n]=(float)wv;
    #pragma unroll
    for (int e=0;e<15;e++) cl[CD_BC+e*Npts+n]=(float)Bc_n[e];
  }
  if (lane==0){
    cl[CD_WSUM]=(float)wsum;
    cl[CD_LAMK]=(float)(lam/(double)Kb);
    #pragma unroll
    for (int e=0;e<15;e++) cl[CD_BMEAN+e]=(float)Bm[e];
    #pragma unroll
    for (int k=0;k<Kb;k++)
    #pragma unroll
    for (int l=0;l<Kb;l++) cl[CD_GI+k*Kb+l]=(float)GI[k][l];
  }
}

// ---------------- kernels ----------------
__global__ void k_init(const float* __restrict__ kp, const float* __restrict__ corr0,
                       const float* __restrict__ mkp, const float* __restrict__ w,
                       const float* __restrict__ lamp,
                       float* __restrict__ consts, float* __restrict__ posebuf,
                       float* __restrict__ corrbuf, float* __restrict__ savbuf)
{
  int b=blockIdx.x, lane=threadIdx.x, n=lane&31;
  __shared__ float cl[560];
  compute_consts_static(mkp, w, lamp, lane, cl);
  for (int e=lane;e<96;e+=64) corrbuf[b*96+e]=corr0[b*96+e];
  float y[3];
  for (int i=0;i<3;i++) y[i]=kp[b*96+i*Npts+n]+corr0[b*96+i*Npts+n];
  float R3[3][3],tv[3],cc[Kb];
  pace_fwd_wave(y, cl, savbuf+(size_t)b*512, lane, 1, R3, tv, cc);
  if (lane==0){
    float* P=posebuf+b*20;
    for (int i=0;i<3;i++){ P[9+i]=tv[i]; for (int j=0;j<3;j++) P[i*3+j]=R3[i][j]; }
    for (int k=0;k<Kb;k++) P[12+k]=cc[k];
  }
  if (b==0) for (int e=lane;e<560;e+=64) consts[e]=cl[e];
}

// k_cham: chamfer only. 256 blocks x 512 thr. pose -> model -> argmin -> 17 partial sums.
__global__ __launch_bounds__(512,1) void k_cham(const float* __restrict__ pc,
    const float* __restrict__ cad, const float* __restrict__ posebuf,
    float* __restrict__ accbuf)
{
  int blk=blockIdx.x;
  int b=blk>>5, chunk=blk&31;
  int tid=threadIdx.x;
  __shared__ float4 smod[NCAD];
  __shared__ float s_pose[20];
  __shared__ float s_part[8][17];
  if (tid<20) s_pose[tid]=posebuf[b*20+tid];
  __syncthreads();
  float R[9],T[3],C[Kb];
  for (int e=0;e<9;e++) R[e]=s_pose[e];
  for (int i=0;i<3;i++) T[i]=s_pose[9+i];
  for (int k=0;k<Kb;k++) C[k]=s_pose[12+k];
  for (int j=tid;j<NCAD;j+=512){
    float cv[15];
    for (int e=0;e<15;e++) cv[e]=cad[e*NCAD+j];
    float m0=0.f,m1=0.f,m2=0.f;
    for (int k=0;k<Kb;k++){ m0+=C[k]*cv[k*3+0]; m1+=C[k]*cv[k*3+1]; m2+=C[k]*cv[k*3+2]; }
    float ax=R[0]*m0+R[1]*m1+R[2]*m2+T[0];
    float ay=R[3]*m0+R[4]*m1+R[5]*m2+T[1];
    float az=R[6]*m0+R[7]*m1+R[8]*m2+T[2];
    smod[j]=make_float4(ax,ay,az, ax*ax+ay*ay+az*az);
  }
  __syncthreads();
  int pr=tid>>4, q=tid&15;
  int pbase=chunk*PPB+pr*4;
  const float* pcb=pc+(size_t)b*3*Mpc;
  float px0=pcb[pbase+0],       px1=pcb[pbase+1],       px2=pcb[pbase+2],       px3=pcb[pbase+3];
  float py0=pcb[Mpc+pbase+0],   py1=pcb[Mpc+pbase+1],   py2=pcb[Mpc+pbase+2],   py3=pcb[Mpc+pbase+3];
  float pz0=pcb[2*Mpc+pbase+0], pz1=pcb[2*Mpc+pbase+1], pz2=pcb[2*Mpc+pbase+2], pz3=pcb[2*Mpc+pbase+3];
  float nx0=-2.f*px0, nx1=-2.f*px1, nx2=-2.f*px2, nx3=-2.f*px3;
  float ny0=-2.f*py0, ny1=-2.f*py1, ny2=-2.f*py2, ny3=-2.f*py3;
  float nz0=-2.f*pz0, nz1=-2.f*pz1, nz2=-2.f*pz2, nz3=-2.f*pz3;
  float d0=3.4e38f, d1=3.4e38f, d2=3.4e38f, d3=3.4e38f;
  int j0=0, j1=0, j2=0, j3=0;
  float4 mcur=smod[q];
  int jc=q;
  #pragma unroll 8
  for (int it=0; it<NCAD/16-1; ++it){
    float4 mnext=smod[jc+16];
    float c;
    c=fmaf(nx0,mcur.x,fmaf(ny0,mcur.y,fmaf(nz0,mcur.z,mcur.w))); if(c<d0){d0=c;j0=jc;}
    c=fmaf(nx1,mcur.x,fmaf(ny1,mcur.y,fmaf(nz1,mcur.z,mcur.w))); if(c<d1){d1=c;j1=jc;}
    c=fmaf(nx2,mcur.x,fmaf(ny2,mcur.y,fmaf(nz2,mcur.z,mcur.w))); if(c<d2){d2=c;j2=jc;}
    c=fmaf(nx3,mcur.x,fmaf(ny3,mcur.y,fmaf(nz3,mcur.z,mcur.w))); if(c<d3){d3=c;j3=jc;}
    mcur=mnext; jc+=16;
  }
  {
    float c;
    c=fmaf(nx0,mcur.x,fmaf(ny0,mcur.y,fmaf(nz0,mcur.z,mcur.w))); if(c<d0){d0=c;j0=jc;}
    c=fmaf(nx1,mcur.x,fmaf(ny1,mcur.y,fmaf(nz1,mcur.z,mcur.w))); if(c<d1){d1=c;j1=jc;}
    c=fmaf(nx2,mcur.x,fmaf(ny2,mcur.y,fmaf(nz2,mcur.z,mcur.w))); if(c<d2){d2=c;j2=jc;}
    c=fmaf(nx3,mcur.x,fmaf(ny3,mcur.y,fmaf(nz3,mcur.z,mcur.w))); if(c<d3){d3=c;j3=jc;}
  }
  #define DPPMIN(dd,jj,ctrl) { \
    float od=__int_as_float(__builtin_amdgcn_update_dpp(0,__float_as_int(dd),ctrl,0xf,0xf,true)); \
    int   oj=__builtin_amdgcn_update_dpp(0,jj,ctrl,0xf,0xf,true); \
    if(od<dd||(od==dd&&oj<jj)){dd=od;jj=oj;} }
  DPPMIN(d0,j0,0xB1) DPPMIN(d0,j0,0x4E) DPPMIN(d0,j0,0x141) DPPMIN(d0,j0,0x140)
  DPPMIN(d1,j1,0xB1) DPPMIN(d1,j1,0x4E) DPPMIN(d1,j1,0x141) DPPMIN(d1,j1,0x140)
  DPPMIN(d2,j2,0xB1) DPPMIN(d2,j2,0x4E) DPPMIN(d2,j2,0x141) DPPMIN(d2,j2,0x140)
  DPPMIN(d3,j3,0xB1) DPPMIN(d3,j3,0x4E) DPPMIN(d3,j3,0x141) DPPMIN(d3,j3,0x140)
  #undef DPPMIN
  float vals[17];
  for (int v=0;v<17;v++) vals[v]=0.f;
  if (q<4){
    float selx=(q==0)?px0:(q==1)?px1:(q==2)?px2:px3;
    float sely=(q==0)?py0:(q==1)?py1:(q==2)?py2:py3;
    float selz=(q==0)?pz0:(q==1)?pz1:(q==2)?pz2:pz3;
    int   selj=(q==0)?j0 :(q==1)?j1 :(q==2)?j2 :j3;
    float4 m=smod[selj];
    float md0=m.x-selx, md1=m.y-sely, md2=m.z-selz;
    float cv[15];
    for (int e=0;e<15;e++) cv[e]=cad[e*NCAD+selj];
    float m00=0.f,m01=0.f,m02=0.f;
    for (int k=0;k<Kb;k++){ m00+=C[k]*cv[k*3+0]; m01+=C[k]*cv[k*3+1]; m02+=C[k]*cv[k*3+2]; }
    vals[0]=md0; vals[1]=md1; vals[2]=md2;
    vals[3]=md0*m00; vals[4]=md0*m01; vals[5]=md0*m02;
    vals[6]=md1*m00; vals[7]=md1*m01; vals[8]=md1*m02;
    vals[9]=md2*m00; vals[10]=md2*m01; vals[11]=md2*m02;
    float t0=R[0]*md0+R[3]*md1+R[6]*md2;
    float t1=R[1]*md0+R[4]*md1+R[7]*md2;
    float t2=R[2]*md0+R[5]*md1+R[8]*md2;
    for (int k=0;k<Kb;k++) vals[12+k]=t0*cv[k*3+0]+t1*cv[k*3+1]+t2*cv[k*3+2];
  }
  for (int v=0;v<17;v++) vals[v]=wsum64(vals[v]);
  int wv=tid>>6;
  if ((tid&63)==0) for (int v=0;v<17;v++) s_part[wv][v]=vals[v];
  __syncthreads();
  if (tid<17){
    float a=0.f;
    for (int w=0;w<8;w++) a+=s_part[w][tid];
    accbuf[(b*NCHUNK+chunk)*20+tid]=a;
  }
}

// k_pace: PACE bwd + corr update + fwd. 8 blocks x 64 thr. last==1 writes outputs.
__global__ void k_pace(const float* __restrict__ kp, const float* __restrict__ consts,
                       const float* __restrict__ accbuf, float* __restrict__ savbuf,
                       float* __restrict__ corrbuf, float* __restrict__ posebuf,
                       float* __restrict__ out, int last)
{
  int b=blockIdx.x, lane=threadIdx.x, n=lane&31;
  __shared__ float s_cl[560];
  __shared__ float s_sav[512];
  __shared__ float s_red[17];
  for (int e=lane;e<560;e+=64) s_cl[e]=consts[e];
  for (int e=lane;e<512;e+=64) s_sav[e]=savbuf[(size_t)b*512+e];
  if (lane<17){
    float a=0.f;
    for (int ch=0;ch<NCHUNK;ch++) a+=accbuf[(b*NCHUNK+ch)*20+lane];
    s_red[lane]=a*(2.0f/(float)Mpc);
  }
  __syncthreads();
  float red[17];
  for (int v=0;v<17;v++) red[v]=s_red[v];
  float dy[3];
  pace_bwd_wave(red, s_cl, s_sav, lane, dy);
  float newc[3];
  for (int i=0;i<3;i++) newc[i]=corrbuf[b*96+i*Npts+n]-0.5f*dy[i];
  float y[3];
  for (int i=0;i<3;i++) y[i]=kp[b*96+i*Npts+n]+newc[i];
  __syncthreads();
  float R3[3][3],tv[3],cc[Kb];
  pace_fwd_wave(y, s_cl, s_sav, lane, last?0:1, R3, tv, cc);
  if (!last){
    if (lane<32) for (int i=0;i<3;i++) corrbuf[b*96+i*Npts+n]=newc[i];
    if (lane==0){
      float* P=posebuf+b*20;
      for (int i=0;i<3;i++){ P[9+i]=tv[i]; for (int j=0;j<3;j++) P[i*3+j]=R3[i][j]; }
      for (int k=0;k<Kb;k++) P[12+k]=cc[k];
    }
    __syncthreads();
    for (int e=lane;e<512;e+=64) savbuf[(size_t)b*512+e]=s_sav[e];
  } else {
    if (lane==0){
      for (int i=0;i<3;i++) for (int j=0;j<3;j++) out[b*9+i*3+j]=R3[i][j];
      for (int i=0;i<3;i++) out[72+b*3+i]=tv[i];
      for (int k=0;k<Kb;k++) out[96+b*Kb+k]=cc[k];
    }
    if (lane<32){
      for (int i=0;i<3;i++){
        out[136+b*96+i*Npts+n]=newc[i];
        out[904+b*96+i*Npts+n]=kp[b*96+i*Npts+n]+newc[i];
      }
    }
  }
}

extern "C" void kernel_launch(void* const* d_in, const int* in_sizes, int n_in,
                              void* d_out, int out_size, void* d_ws, size_t ws_size,
                              hipStream_t stream) {
  const float* pc   =(const float*)d_in[0];
  const float* kp   =(const float*)d_in[1];
  const float* corr0=(const float*)d_in[2];
  const float* mkp  =(const float*)d_in[3];
  const float* cad  =(const float*)d_in[4];
  const float* w    =(const float*)d_in[5];
  const float* lam  =(const float*)d_in[6];
  float* out=(float*)d_out;
  char* ws=(char*)d_ws;
  float* consts =(float*)(ws+0);        // 560
  float* posebuf=(float*)(ws+4096);     // 160
  float* corrbuf=(float*)(ws+8192);     // 768
  float* savbuf =(float*)(ws+16384);    // 8*512
  float* accbuf =(float*)(ws+49152);    // 8*32*20

  hipLaunchKernelGGL(k_init, dim3(Bsz), dim3(64), 0, stream,
                     kp, corr0, mkp, w, lam, consts, posebuf, corrbuf, savbuf);
  for (int s=0; s<NSTEPS; ++s){
    hipLaunchKernelGGL(k_cham, dim3(Bsz*NCHUNK), dim3(512), 0, stream,
                       pc, cad, posebuf, accbuf);
    hipLaunchKernelGGL(k_pace, dim3(Bsz), dim3(64), 0, stream,
                       kp, consts, accbuf, savbuf, corrbuf, posebuf, out, (s==NSTEPS-1)?1:0);
  }
}